// Round 1
// baseline (2495.482 us; speedup 1.0000x reference)
//
#include <hip/hip_runtime.h>
#include <math.h>

// Problem constants: B=16, L=64, H=512, N_LABELS=64, ITERS=3
// ws layout (floats):
//   wt      [512*512]  = W_ID transposed (wt[h*512+g] = W_ID[g*512+h])
//   sfbuf   [B*L*H]    = slot_features
//   r_slot  [B*L*H]
//   hid     [B*L*H]
//   tmp     [B*H]      = r_inte @ W_SF.T
//   tsum    [B*H]      = sum_l tanh(c_slot + tmp)
//   fbuf    [B*H]      = tsum @ V_SF.T
//   r_inte  [B*H]
//   smat    [L*L]
//   atts    [L]

__global__ __launch_bounds__(256) void k_transpose(const float* __restrict__ in,
                                                   float* __restrict__ out) {
  int idx = blockIdx.x * 256 + threadIdx.x;  // 262144
  int h = idx >> 9, g = idx & 511;
  out[idx] = in[g * 512 + h];
}

__global__ __launch_bounds__(256) void k_copy(const float* __restrict__ in,
                                              float* __restrict__ out, int n) {
  int idx = blockIdx.x * 256 + threadIdx.x;
  if (idx < n) out[idx] = in[idx];
}

__global__ __launch_bounds__(256) void k_zero(float* __restrict__ p, int n) {
  int idx = blockIdx.x * 256 + threadIdx.x;
  if (idx < n) p[idx] = 0.f;
}

// C[M,N] = A[M,512] @ Bw[N,512]^T (+bias). Tile 64x64, K-tile 32, 4x4 micro.
__global__ __launch_bounds__(256) void k_gemm64(const float* __restrict__ A,
                                                const float* __restrict__ Bw,
                                                const float* __restrict__ bias,
                                                float* __restrict__ C, int N) {
  __shared__ float As[32][65];
  __shared__ float Bs[32][65];
  const int m0 = blockIdx.y * 64, n0 = blockIdx.x * 64;
  const int t = threadIdx.x;
  const int tm = t >> 4, tn = t & 15;
  float acc[4][4] = {};
  for (int k0 = 0; k0 < 512; k0 += 32) {
    for (int e = t; e < 2048; e += 256) {
      int row = e >> 5, kk = e & 31;
      As[kk][row] = A[(m0 + row) * 512 + k0 + kk];
      Bs[kk][row] = Bw[(n0 + row) * 512 + k0 + kk];
    }
    __syncthreads();
#pragma unroll
    for (int kk = 0; kk < 32; ++kk) {
      float a[4], b[4];
#pragma unroll
      for (int r = 0; r < 4; ++r) a[r] = As[kk][tm + 16 * r];
#pragma unroll
      for (int c = 0; c < 4; ++c) b[c] = Bs[kk][tn + 16 * c];
#pragma unroll
      for (int r = 0; r < 4; ++r)
#pragma unroll
        for (int c = 0; c < 4; ++c) acc[r][c] += a[r] * b[c];
    }
    __syncthreads();
  }
#pragma unroll
  for (int r = 0; r < 4; ++r)
#pragma unroll
    for (int c = 0; c < 4; ++c) {
      int m = m0 + tm + 16 * r, n = n0 + tn + 16 * c;
      float v = acc[r][c];
      if (bias) v += bias[n];
      C[m * N + n] = v;
    }
}

// C[16,512] = A[16,512] @ Bw[512,512]^T  (tiny GEMM, naive per-output)
__global__ __launch_bounds__(256) void k_gemm16(const float* __restrict__ A,
                                                const float* __restrict__ Bw,
                                                float* __restrict__ C) {
  int idx = blockIdx.x * 256 + threadIdx.x;  // 8192
  int b = idx >> 9, n = idx & 511;
  const float* a = A + b * 512;
  const float* w = Bw + n * 512;
  float acc = 0.f;
  for (int k = 0; k < 512; ++k) acc += a[k] * w[k];
  C[idx] = acc;
}

// tsum[b,h] = sum_l tanh(c_slot[b,l,h] + tmp[b,h])
__global__ __launch_bounds__(256) void k_tsum(const float* __restrict__ c_slot,
                                              const float* __restrict__ tmp,
                                              float* __restrict__ tsum) {
  int idx = blockIdx.x * 256 + threadIdx.x;  // 8192
  int b = idx >> 9, hh = idx & 511;
  float t0 = tmp[idx];
  float acc = 0.f;
  for (int l = 0; l < 64; ++l) acc += tanhf(c_slot[(b * 64 + l) * 512 + hh] + t0);
  tsum[idx] = acc;
}

// r_slot[b,l,h] = fbuf[b,h] * c_slot[b,l,h]
__global__ __launch_bounds__(256) void k_rslot(const float* __restrict__ fbuf,
                                               const float* __restrict__ c_slot,
                                               float* __restrict__ r_slot) {
  int idx = blockIdx.x * 256 + threadIdx.x;  // 524288
  int b = idx >> 15, hh = idx & 511;
  r_slot[idx] = fbuf[(b << 9) | hh] * c_slot[idx];
}

// The dominant fused kernel:
// smat[i,j] += sum_g exp( sum_h tanh(hid[b,i,h]+sf[b,j,h]) * W_ID[g,h] )  (atomic over b)
// Block: fixed (b, i), 16 consecutive j's (rows), all 512 g's (cols).
// Thread micro-tile: 4 rows x 8 cols; K-tile 16.
__global__ __launch_bounds__(256) void k_score(const float* __restrict__ hid,
                                               const float* __restrict__ sf,
                                               const float* __restrict__ wt,
                                               float* __restrict__ smat) {
  __shared__ float As[16][16];
  __shared__ __align__(16) float Bs[16][512];
  const int b = blockIdx.y;
  const int p0 = blockIdx.x * 16;   // pair base; p = i*64 + j
  const int t = threadIdx.x;
  const int tr = t >> 6;            // wave id 0..3 -> owns rows tr+4*r
  const int tc = t & 63;            // lane -> owns cols tc*8 .. tc*8+7
  const int i = p0 >> 6;            // constant within block (p0 % 64 + 15 < 64)
  const int j0 = p0 & 63;

  float acc[4][8];
#pragma unroll
  for (int r = 0; r < 4; ++r)
#pragma unroll
    for (int c = 0; c < 8; ++c) acc[r][c] = 0.f;

  const float* hrow = hid + (b * 64 + i) * 512;
  const float* srow0 = sf + (b * 64 + j0) * 512;

  const int arow = t >> 4, akk = t & 15;  // A staging assignment (1 elem/thread)

  for (int k0 = 0; k0 < 512; k0 += 16) {
    // Stage A tile: As[row][k] = tanh(hid[b,i,k0+k] + sf[b,j0+row,k0+k])
    {
      float x = hrow[k0 + akk] + srow0[arow * 512 + k0 + akk];
      As[arow][akk] = tanhf(x);
    }
    // Stage B tile: Bs[k][g] = wt[(k0+k)*512 + g], contiguous 32KB copy
    {
      const float4* src = (const float4*)(wt + k0 * 512);
      float4* dst = (float4*)(&Bs[0][0]);
#pragma unroll
      for (int e = 0; e < 8; ++e) dst[t + 256 * e] = src[t + 256 * e];
    }
    __syncthreads();
#pragma unroll
    for (int kk = 0; kk < 16; ++kk) {
      float aa[4];
      aa[0] = As[tr][kk];
      aa[1] = As[tr + 4][kk];
      aa[2] = As[tr + 8][kk];
      aa[3] = As[tr + 12][kk];
      float bb[8];
      *(float4*)&bb[0] = *(const float4*)(&Bs[kk][tc * 8]);
      *(float4*)&bb[4] = *(const float4*)(&Bs[kk][tc * 8 + 4]);
#pragma unroll
      for (int r = 0; r < 4; ++r)
#pragma unroll
        for (int c = 0; c < 8; ++c) acc[r][c] += aa[r] * bb[c];
    }
    __syncthreads();
  }

  // Epilogue: exp, reduce over this thread's 8 cols, wave-reduce over 64 lanes
  // (covers all 512 g), one atomicAdd per (row, wave).
#pragma unroll
  for (int r = 0; r < 4; ++r) {
    float v = 0.f;
#pragma unroll
    for (int c = 0; c < 8; ++c) v += expf(acc[r][c]);
    v += __shfl_down(v, 32);
    v += __shfl_down(v, 16);
    v += __shfl_down(v, 8);
    v += __shfl_down(v, 4);
    v += __shfl_down(v, 2);
    v += __shfl_down(v, 1);
    if (tc == 0) atomicAdd(&smat[p0 + tr + 4 * r], v);
  }
}

// atts[i] = smat[i,i] / sum_j smat[i,j]
__global__ void k_atts(const float* __restrict__ smat, float* __restrict__ atts) {
  int i = threadIdx.x;  // 64 threads
  float sum = 0.f;
  for (int j = 0; j < 64; ++j) sum += smat[i * 64 + j];
  atts[i] = smat[i * 64 + i] / sum;
}

// r_inte[b,h] = c_inte[b,h] + sum_i atts[i]*r_slot[b,i,h]
__global__ __launch_bounds__(256) void k_rinte(const float* __restrict__ atts,
                                               const float* __restrict__ r_slot,
                                               const float* __restrict__ c_inte,
                                               float* __restrict__ r_inte) {
  int idx = blockIdx.x * 256 + threadIdx.x;  // 8192
  int b = idx >> 9, hh = idx & 511;
  float acc = 0.f;
  for (int i = 0; i < 64; ++i) acc += atts[i] * r_slot[(b * 64 + i) * 512 + hh];
  r_inte[idx] = acc + c_inte[idx];
}

// intent[b,n] = sum_k r_inte[b,k]*W[n,k] + sum_k h[b,63,k]*W[n,512+k]
__global__ __launch_bounds__(256) void k_intent(const float* __restrict__ r_inte,
                                                const float* __restrict__ h,
                                                const float* __restrict__ W,
                                                float* __restrict__ out) {
  int idx = blockIdx.x * 256 + threadIdx.x;  // 1024
  int b = idx >> 6, n = idx & 63;
  const float* w0 = W + n * 1024;
  const float* r = r_inte + b * 512;
  const float* hl = h + (b * 64 + 63) * 512;
  float acc = 0.f;
  for (int k = 0; k < 512; ++k) acc += r[k] * w0[k];
  for (int k = 0; k < 512; ++k) acc += hl[k] * w0[512 + k];
  out[idx] = acc;
}

// slot[(b,l),n] = sum_k h[b,l,k]*W[n,k] + sum_k r_slot[b,l,k]*W[n,512+k]
__global__ __launch_bounds__(256) void k_slot(const float* __restrict__ h,
                                              const float* __restrict__ r_slot,
                                              const float* __restrict__ W,
                                              float* __restrict__ out) {
  int idx = blockIdx.x * 256 + threadIdx.x;  // 65536
  int ml = idx >> 6, n = idx & 63;
  const float* w0 = W + n * 1024;
  const float* hh = h + ml * 512;
  const float* rs = r_slot + ml * 512;
  float acc = 0.f;
  for (int k = 0; k < 512; ++k) acc += hh[k] * w0[k];
  for (int k = 0; k < 512; ++k) acc += rs[k] * w0[512 + k];
  out[idx] = acc;
}

extern "C" void kernel_launch(void* const* d_in, const int* in_sizes, int n_in,
                              void* d_out, int out_size, void* d_ws, size_t ws_size,
                              hipStream_t stream) {
  const float* h      = (const float*)d_in[0];
  const float* c_slot = (const float*)d_in[1];
  const float* c_inte = (const float*)d_in[2];
  const float* W_SF   = (const float*)d_in[3];
  const float* V_SF   = (const float*)d_in[4];
  const float* V1_ID  = (const float*)d_in[5];
  const float* V2_w   = (const float*)d_in[6];
  const float* V2_b   = (const float*)d_in[7];
  const float* W_ID   = (const float*)d_in[8];
  const float* W_ia   = (const float*)d_in[9];
  const float* W_sa   = (const float*)d_in[10];
  float* out = (float*)d_out;

  float* ws     = (float*)d_ws;
  float* wt     = ws;             // 262144
  float* sfbuf  = ws + 262144;    // 524288
  float* r_slot = ws + 786432;    // 524288
  float* hid    = ws + 1310720;   // 524288
  float* tmp    = ws + 1835008;   // 8192
  float* tsum   = ws + 1843200;   // 8192
  float* fbuf   = ws + 1851392;   // 8192
  float* r_inte = ws + 1859584;   // 8192
  float* smat   = ws + 1867776;   // 4096
  float* atts   = ws + 1871872;   // 64

  // One-time (per call) prep
  k_transpose<<<1024, 256, 0, stream>>>(W_ID, wt);
  k_gemm64<<<dim3(8, 16), 256, 0, stream>>>(h, V2_w, V2_b, sfbuf, 512);
  k_copy<<<32, 256, 0, stream>>>(c_inte, r_inte, 8192);

  for (int it = 0; it < 3; ++it) {
    k_gemm16<<<32, 256, 0, stream>>>(r_inte, W_SF, tmp);
    k_tsum<<<32, 256, 0, stream>>>(c_slot, tmp, tsum);
    k_gemm16<<<32, 256, 0, stream>>>(tsum, V_SF, fbuf);
    k_rslot<<<2048, 256, 0, stream>>>(fbuf, c_slot, r_slot);
    k_gemm64<<<dim3(8, 16), 256, 0, stream>>>(r_slot, V1_ID, nullptr, hid, 512);
    k_zero<<<16, 256, 0, stream>>>(smat, 4096);
    k_score<<<dim3(256, 16), 256, 0, stream>>>(hid, sfbuf, wt, smat);
    k_atts<<<1, 64, 0, stream>>>(smat, atts);
    k_rinte<<<32, 256, 0, stream>>>(atts, r_slot, c_inte, r_inte);
  }

  k_intent<<<4, 256, 0, stream>>>(r_inte, h, W_ia, out);
  k_slot<<<256, 256, 0, stream>>>(h, r_slot, W_sa, out + 1024);
}

// Round 2
// 980.097 us; speedup vs baseline: 2.5462x; 2.5462x over previous
//
#include <hip/hip_runtime.h>
#include <math.h>

// Problem constants: B=16, L=64, H=512, N_LABELS=64, ITERS=3
//
// ws layout (float offsets):
//   wbp    [262144 shorts = 131072 f]  W_ID packed bf16, B-fragment-major:
//          flat = (((nblk*16 + kstep)*16 + ntile)*64 + lane)*8 + j
//          value = bf16( W_ID[ nblk*256 + ntile*16 + (lane&15) ]
//                            [ kstep*32 + (lane>>4)*8 + j ] )
//   sfbuf  [B*L*H]   slot_features (f32)
//   r_slot [B*L*H]
//   hid    [B*L*H]
//   tmp/tsum/fbuf/r_inte [B*H] each
//   smat   [L*L], atts [L]

typedef __attribute__((ext_vector_type(8))) short bf16x8;
typedef __attribute__((ext_vector_type(4))) float f32x4;

__device__ inline short f2bf(float x) {
  unsigned u = __float_as_uint(x);
  unsigned r = (u + 0x7fffu + ((u >> 16) & 1u)) >> 16;
  return (short)r;
}

__global__ __launch_bounds__(256) void k_pack(const float* __restrict__ W_ID,
                                              short* __restrict__ wbp) {
  int idx = blockIdx.x * 256 + threadIdx.x;  // 262144
  int j = idx & 7;
  int lane = (idx >> 3) & 63;
  int ntile = (idx >> 9) & 15;
  int kstep = (idx >> 13) & 15;
  int nblk = idx >> 17;
  int g = nblk * 256 + ntile * 16 + (lane & 15);
  int h = kstep * 32 + (lane >> 4) * 8 + j;
  wbp[idx] = f2bf(W_ID[g * 512 + h]);
}

__global__ __launch_bounds__(256) void k_copy(const float* __restrict__ in,
                                              float* __restrict__ out, int n) {
  int idx = blockIdx.x * 256 + threadIdx.x;
  if (idx < n) out[idx] = in[idx];
}

__global__ __launch_bounds__(256) void k_zero(float* __restrict__ p, int n) {
  int idx = blockIdx.x * 256 + threadIdx.x;
  if (idx < n) p[idx] = 0.f;
}

// C[M,N] = A[M,512] @ Bw[N,512]^T (+bias). Tile 64x64, K-tile 32, 4x4 micro.
__global__ __launch_bounds__(256) void k_gemm64(const float* __restrict__ A,
                                                const float* __restrict__ Bw,
                                                const float* __restrict__ bias,
                                                float* __restrict__ C, int N) {
  __shared__ float As[32][65];
  __shared__ float Bs[32][65];
  const int m0 = blockIdx.y * 64, n0 = blockIdx.x * 64;
  const int t = threadIdx.x;
  const int tm = t >> 4, tn = t & 15;
  float acc[4][4] = {};
  for (int k0 = 0; k0 < 512; k0 += 32) {
    for (int e = t; e < 2048; e += 256) {
      int row = e >> 5, kk = e & 31;
      As[kk][row] = A[(m0 + row) * 512 + k0 + kk];
      Bs[kk][row] = Bw[(n0 + row) * 512 + k0 + kk];
    }
    __syncthreads();
#pragma unroll
    for (int kk = 0; kk < 32; ++kk) {
      float a[4], b[4];
#pragma unroll
      for (int r = 0; r < 4; ++r) a[r] = As[kk][tm + 16 * r];
#pragma unroll
      for (int c = 0; c < 4; ++c) b[c] = Bs[kk][tn + 16 * c];
#pragma unroll
      for (int r = 0; r < 4; ++r)
#pragma unroll
        for (int c = 0; c < 4; ++c) acc[r][c] += a[r] * b[c];
    }
    __syncthreads();
  }
#pragma unroll
  for (int r = 0; r < 4; ++r)
#pragma unroll
    for (int c = 0; c < 4; ++c) {
      int m = m0 + tm + 16 * r, n = n0 + tn + 16 * c;
      float v = acc[r][c];
      if (bias) v += bias[n];
      C[m * N + n] = v;
    }
}

// C[16,512] = A[16,512] @ Bw[512,512]^T  (tiny GEMM, naive per-output)
__global__ __launch_bounds__(256) void k_gemm16(const float* __restrict__ A,
                                                const float* __restrict__ Bw,
                                                float* __restrict__ C) {
  int idx = blockIdx.x * 256 + threadIdx.x;  // 8192
  int b = idx >> 9, n = idx & 511;
  const float* a = A + b * 512;
  const float* w = Bw + n * 512;
  float acc = 0.f;
  for (int k = 0; k < 512; ++k) acc += a[k] * w[k];
  C[idx] = acc;
}

// tsum[b,h] = sum_l tanh(c_slot[b,l,h] + tmp[b,h])
__global__ __launch_bounds__(256) void k_tsum(const float* __restrict__ c_slot,
                                              const float* __restrict__ tmp,
                                              float* __restrict__ tsum) {
  int idx = blockIdx.x * 256 + threadIdx.x;  // 8192
  int b = idx >> 9, hh = idx & 511;
  float t0 = tmp[idx];
  float acc = 0.f;
  for (int l = 0; l < 64; ++l) acc += tanhf(c_slot[(b * 64 + l) * 512 + hh] + t0);
  tsum[idx] = acc;
}

// r_slot[b,l,h] = fbuf[b,h] * c_slot[b,l,h]
__global__ __launch_bounds__(256) void k_rslot(const float* __restrict__ fbuf,
                                               const float* __restrict__ c_slot,
                                               float* __restrict__ r_slot) {
  int idx = blockIdx.x * 256 + threadIdx.x;  // 524288
  int b = idx >> 15, hh = idx & 511;
  r_slot[idx] = fbuf[(b << 9) | hh] * c_slot[idx];
}

// Dominant kernel, MFMA version.
// smat[i,j] += sum_g exp( sum_h tanh(hid[b,i,h]+sf[b,j,h]) * W_ID[g,h] )
// Block = (i, b, nblk): output 64 j x 256 g, K=512, K-tile 32.
// 4 waves; wave w owns g-tiles [w*4 .. w*4+3] (64 g columns).
// A staged to LDS in A-fragment order (lane-contiguous b128), B tile is a
// contiguous 16KB copy of the pre-packed fragment-major wbp.
__global__ __launch_bounds__(256) void k_score_mfma(const float* __restrict__ hid,
                                                    const float* __restrict__ sf,
                                                    const short* __restrict__ wbp,
                                                    float* __restrict__ smat) {
  __shared__ short As[4 * 64 * 8];    // 4 KB  [mtile][lane][8]
  __shared__ short Bs[16 * 64 * 8];   // 16 KB [ntile][lane][8]
  const int i = blockIdx.x;       // 0..63
  const int b = blockIdx.y;       // 0..15
  const int nblk = blockIdx.z;    // 0..1
  const int t = threadIdx.x;
  const int w = t >> 6;
  const int lane = t & 63;
  const int lq = lane >> 4;
  const int lm = lane & 15;

  f32x4 acc[4][4];
#pragma unroll
  for (int r = 0; r < 4; ++r)
#pragma unroll
    for (int c = 0; c < 4; ++c) acc[r][c] = (f32x4){0.f, 0.f, 0.f, 0.f};

  const float* hrow = hid + (b * 64 + i) * 512;
  const float* sfb = sf + b * 64 * 512;
  const short* wnb = wbp + nblk * 131072;  // 16 ksteps * 8192

  // A-staging assignment: thread t -> (mtile = t>>6, frag-lane = t&63)
  const int amt = t >> 6;
  const int am = amt * 16 + (t & 15);        // j row 0..63
  const int akk = ((t >> 4) & 3) * 8;        // k offset within K-tile

  for (int ks = 0; ks < 16; ++ks) {
    const int k0 = ks * 32;
    // --- stage A: tanh(hid + sf) -> bf16, fragment order ---
    {
      const float* hp = hrow + k0 + akk;
      const float* sp = sfb + am * 512 + k0 + akk;
      float4 h0 = *(const float4*)(hp);
      float4 h1 = *(const float4*)(hp + 4);
      float4 s0 = *(const float4*)(sp);
      float4 s1 = *(const float4*)(sp + 4);
      bf16x8 av;
      av[0] = f2bf(tanhf(h0.x + s0.x));
      av[1] = f2bf(tanhf(h0.y + s0.y));
      av[2] = f2bf(tanhf(h0.z + s0.z));
      av[3] = f2bf(tanhf(h0.w + s0.w));
      av[4] = f2bf(tanhf(h1.x + s1.x));
      av[5] = f2bf(tanhf(h1.y + s1.y));
      av[6] = f2bf(tanhf(h1.z + s1.z));
      av[7] = f2bf(tanhf(h1.w + s1.w));
      *((bf16x8*)&As[t * 8]) = av;
    }
    // --- stage B: contiguous 16KB copy ---
    {
      const uint4* src = (const uint4*)(wnb + ks * 8192);
      uint4* dst = (uint4*)Bs;
      dst[t] = src[t];
      dst[t + 256] = src[t + 256];
      dst[t + 512] = src[t + 512];
      dst[t + 768] = src[t + 768];
    }
    __syncthreads();
    bf16x8 af[4], bf[4];
#pragma unroll
    for (int r = 0; r < 4; ++r) af[r] = *((const bf16x8*)&As[(r * 64 + lane) * 8]);
#pragma unroll
    for (int c = 0; c < 4; ++c)
      bf[c] = *((const bf16x8*)&Bs[((w * 4 + c) * 64 + lane) * 8]);
#pragma unroll
    for (int r = 0; r < 4; ++r)
#pragma unroll
      for (int c = 0; c < 4; ++c)
        acc[r][c] = __builtin_amdgcn_mfma_f32_16x16x32_bf16(af[r], bf[c], acc[r][c], 0, 0, 0);
    __syncthreads();
  }

  // Epilogue: exp + reduce over g. C/D layout: col = lm, row = lq*4 + reg.
#pragma unroll
  for (int r = 0; r < 4; ++r) {
#pragma unroll
    for (int reg = 0; reg < 4; ++reg) {
      float v = expf(acc[r][0][reg]) + expf(acc[r][1][reg]) +
                expf(acc[r][2][reg]) + expf(acc[r][3][reg]);
      v += __shfl_down(v, 8, 16);
      v += __shfl_down(v, 4, 16);
      v += __shfl_down(v, 2, 16);
      v += __shfl_down(v, 1, 16);
      if (lm == 0) {
        int row = r * 16 + lq * 4 + reg;  // j
        atomicAdd(&smat[i * 64 + row], v);
      }
    }
  }
}

// atts[i] = smat[i,i] / sum_j smat[i,j]
__global__ void k_atts(const float* __restrict__ smat, float* __restrict__ atts) {
  int i = threadIdx.x;  // 64 threads
  float sum = 0.f;
  for (int j = 0; j < 64; ++j) sum += smat[i * 64 + j];
  atts[i] = smat[i * 64 + i] / sum;
}

// r_inte[b,h] = c_inte[b,h] + sum_i atts[i]*r_slot[b,i,h]
__global__ __launch_bounds__(256) void k_rinte(const float* __restrict__ atts,
                                               const float* __restrict__ r_slot,
                                               const float* __restrict__ c_inte,
                                               float* __restrict__ r_inte) {
  int idx = blockIdx.x * 256 + threadIdx.x;  // 8192
  int b = idx >> 9, hh = idx & 511;
  float acc = 0.f;
  for (int i = 0; i < 64; ++i) acc += atts[i] * r_slot[(b * 64 + i) * 512 + hh];
  r_inte[idx] = acc + c_inte[idx];
}

// intent[b,n] = sum_k r_inte[b,k]*W[n,k] + sum_k h[b,63,k]*W[n,512+k]
__global__ __launch_bounds__(256) void k_intent(const float* __restrict__ r_inte,
                                                const float* __restrict__ h,
                                                const float* __restrict__ W,
                                                float* __restrict__ out) {
  int idx = blockIdx.x * 256 + threadIdx.x;  // 1024
  int b = idx >> 6, n = idx & 63;
  const float* w0 = W + n * 1024;
  const float* r = r_inte + b * 512;
  const float* hl = h + (b * 64 + 63) * 512;
  float acc = 0.f;
  for (int k = 0; k < 512; ++k) acc += r[k] * w0[k];
  for (int k = 0; k < 512; ++k) acc += hl[k] * w0[512 + k];
  out[idx] = acc;
}

// slot[(b,l),n] = sum_k h[b,l,k]*W[n,k] + sum_k r_slot[b,l,k]*W[n,512+k]
__global__ __launch_bounds__(256) void k_slot(const float* __restrict__ h,
                                              const float* __restrict__ r_slot,
                                              const float* __restrict__ W,
                                              float* __restrict__ out) {
  int idx = blockIdx.x * 256 + threadIdx.x;  // 65536
  int ml = idx >> 6, n = idx & 63;
  const float* w0 = W + n * 1024;
  const float* hh = h + ml * 512;
  const float* rs = r_slot + ml * 512;
  float acc = 0.f;
  for (int k = 0; k < 512; ++k) acc += hh[k] * w0[k];
  for (int k = 0; k < 512; ++k) acc += rs[k] * w0[512 + k];
  out[idx] = acc;
}

extern "C" void kernel_launch(void* const* d_in, const int* in_sizes, int n_in,
                              void* d_out, int out_size, void* d_ws, size_t ws_size,
                              hipStream_t stream) {
  const float* h      = (const float*)d_in[0];
  const float* c_slot = (const float*)d_in[1];
  const float* c_inte = (const float*)d_in[2];
  const float* W_SF   = (const float*)d_in[3];
  const float* V_SF   = (const float*)d_in[4];
  const float* V1_ID  = (const float*)d_in[5];
  const float* V2_w   = (const float*)d_in[6];
  const float* V2_b   = (const float*)d_in[7];
  const float* W_ID   = (const float*)d_in[8];
  const float* W_ia   = (const float*)d_in[9];
  const float* W_sa   = (const float*)d_in[10];
  float* out = (float*)d_out;

  float* ws     = (float*)d_ws;
  short* wbp    = (short*)ws;      // 262144 shorts = 131072 floats
  float* sfbuf  = ws + 131072;     // 524288
  float* r_slot = ws + 655360;     // 524288
  float* hid    = ws + 1179648;    // 524288
  float* tmp    = ws + 1703936;    // 8192
  float* tsum   = ws + 1712128;    // 8192
  float* fbuf   = ws + 1720320;    // 8192
  float* r_inte = ws + 1728512;    // 8192
  float* smat   = ws + 1736704;    // 4096
  float* atts   = ws + 1740800;    // 64

  // One-time (per call) prep
  k_pack<<<1024, 256, 0, stream>>>(W_ID, wbp);
  k_gemm64<<<dim3(8, 16), 256, 0, stream>>>(h, V2_w, V2_b, sfbuf, 512);
  k_copy<<<32, 256, 0, stream>>>(c_inte, r_inte, 8192);

  for (int it = 0; it < 3; ++it) {
    k_gemm16<<<32, 256, 0, stream>>>(r_inte, W_SF, tmp);
    k_tsum<<<32, 256, 0, stream>>>(c_slot, tmp, tsum);
    k_gemm16<<<32, 256, 0, stream>>>(tsum, V_SF, fbuf);
    k_rslot<<<2048, 256, 0, stream>>>(fbuf, c_slot, r_slot);
    k_gemm64<<<dim3(8, 16), 256, 0, stream>>>(r_slot, V1_ID, nullptr, hid, 512);
    k_zero<<<16, 256, 0, stream>>>(smat, 4096);
    k_score_mfma<<<dim3(64, 16, 2), 256, 0, stream>>>(hid, sfbuf, wbp, smat);
    k_atts<<<1, 64, 0, stream>>>(smat, atts);
    k_rinte<<<32, 256, 0, stream>>>(atts, r_slot, c_inte, r_inte);
  }

  k_intent<<<4, 256, 0, stream>>>(r_inte, h, W_ia, out);
  k_slot<<<256, 256, 0, stream>>>(h, r_slot, W_sa, out + 1024);
}

// Round 4
// 723.730 us; speedup vs baseline: 3.4481x; 1.3542x over previous
//
#include <hip/hip_runtime.h>
#include <math.h>

// B=16, L=64, H=512, N_LABELS=64, ITERS=3
//
// ws layout (float offsets):
//   wbp    [131072] W_ID bf16, B-fragment-major:
//          flat = ((kstep*32 + ntile)*64 + lane)*8 + j
//          g = ntile*16 + (lane&15); h = kstep*32 + (lane>>4)*8 + j
//   vh,vl  [131072 each] split-bf16 pack of V2_w (then overwritten with V1_ID)
//   sfbuf/r_slot/hid [524288 each]
//   tsum/fbuf/r_inte [8192 each], smat [4096]

typedef __attribute__((ext_vector_type(8))) short bf16x8;
typedef __attribute__((ext_vector_type(4))) float f32x4;

__device__ inline short f2bf(float x) {
  unsigned u = __float_as_uint(x);
  unsigned r = (u + 0x7fffu + ((u >> 16) & 1u)) >> 16;
  return (short)r;
}
__device__ inline float bf2f(short s) {
  return __uint_as_float(((unsigned)(unsigned short)s) << 16);
}
// tanh(x) = 1 - 2/(exp(2x)+1); exp overflow -> inf -> rcp -> 0 -> +1; exp(-big)=0 -> -1.
__device__ inline float ftanh(float x) {
  float t = __expf(2.f * x);
  return 1.f - 2.f * __builtin_amdgcn_rcpf(t + 1.f);
}

// ---- packing ----
__global__ __launch_bounds__(256) void k_pack(const float* __restrict__ W,
                                              short* __restrict__ dst) {
  int idx = blockIdx.x * 256 + threadIdx.x;  // 262144
  int j = idx & 7, lane = (idx >> 3) & 63;
  int ntile = (idx >> 9) & 31, kstep = idx >> 14;
  int g = ntile * 16 + (lane & 15);
  int h = kstep * 32 + (lane >> 4) * 8 + j;
  dst[idx] = f2bf(W[g * 512 + h]);
}

__global__ __launch_bounds__(256) void k_packv(const float* __restrict__ W,
                                               short* __restrict__ dh,
                                               short* __restrict__ dl) {
  int idx = blockIdx.x * 256 + threadIdx.x;  // 262144
  int j = idx & 7, lane = (idx >> 3) & 63;
  int ntile = (idx >> 9) & 31, kstep = idx >> 14;
  int g = ntile * 16 + (lane & 15);
  int h = kstep * 32 + (lane >> 4) * 8 + j;
  float x = W[g * 512 + h];
  short hi = f2bf(x);
  dh[idx] = hi;
  dl[idx] = f2bf(x - bf2f(hi));
}

__global__ __launch_bounds__(256) void k_copy(const float* __restrict__ in,
                                              float* __restrict__ out, int n) {
  int idx = blockIdx.x * 256 + threadIdx.x;
  if (idx < n) out[idx] = in[idx];
}

// ---- split-precision MFMA linear: C[M,512] = A[M,512] @ W[512,512]^T (+bias)
// grid (M/16, 2); block 256 = 4 waves; wave w owns local ntiles w*4..w*4+3.
__global__ __launch_bounds__(256) void k_lin(const float* __restrict__ A,
                                             const short* __restrict__ bh,
                                             const short* __restrict__ bl,
                                             const float* __restrict__ bias,
                                             float* __restrict__ C) {
  __shared__ short Ah[64 * 8], Al[64 * 8];
  __shared__ short Bh[16 * 64 * 8], Bl[16 * 64 * 8];  // 1024 uint4 each
  const int m0 = blockIdx.x * 16;
  const int nh = blockIdx.y;
  const int t = threadIdx.x;
  const int w = t >> 6, lane = t & 63;
  const int lq = lane >> 4, lm = lane & 15;
  f32x4 acc[4];
#pragma unroll
  for (int c = 0; c < 4; ++c) acc[c] = (f32x4){0.f, 0.f, 0.f, 0.f};

  for (int ks = 0; ks < 16; ++ks) {
    __syncthreads();  // WAR: all waves done reading previous tiles
    if (t < 64) {
      const float* ap = A + (m0 + (t & 15)) * 512 + ks * 32 + (t >> 4) * 8;
      float4 x0 = *(const float4*)ap;
      float4 x1 = *(const float4*)(ap + 4);
      float xs[8] = {x0.x, x0.y, x0.z, x0.w, x1.x, x1.y, x1.z, x1.w};
      bf16x8 hv, lv;
#pragma unroll
      for (int e = 0; e < 8; ++e) {
        short hi = f2bf(xs[e]);
        hv[e] = hi;
        lv[e] = f2bf(xs[e] - bf2f(hi));
      }
      *(bf16x8*)&Ah[t * 8] = hv;
      *(bf16x8*)&Al[t * 8] = lv;
    }
    {
      const uint4* sh = (const uint4*)(bh + (ks * 32 + nh * 16) * 64 * 8);
      const uint4* sl = (const uint4*)(bl + (ks * 32 + nh * 16) * 64 * 8);
      uint4* dh = (uint4*)Bh;
      uint4* dl = (uint4*)Bl;
#pragma unroll
      for (int e = 0; e < 4; ++e) {
        dh[t + 256 * e] = sh[t + 256 * e];
        dl[t + 256 * e] = sl[t + 256 * e];
      }
    }
    __syncthreads();
    bf16x8 ah = *(const bf16x8*)&Ah[lane * 8];
    bf16x8 al = *(const bf16x8*)&Al[lane * 8];
#pragma unroll
    for (int c = 0; c < 4; ++c) {
      bf16x8 vh = *(const bf16x8*)&Bh[((w * 4 + c) * 64 + lane) * 8];
      bf16x8 vl = *(const bf16x8*)&Bl[((w * 4 + c) * 64 + lane) * 8];
      acc[c] = __builtin_amdgcn_mfma_f32_16x16x32_bf16(ah, vh, acc[c], 0, 0, 0);
      acc[c] = __builtin_amdgcn_mfma_f32_16x16x32_bf16(al, vh, acc[c], 0, 0, 0);
      acc[c] = __builtin_amdgcn_mfma_f32_16x16x32_bf16(ah, vl, acc[c], 0, 0, 0);
    }
  }
#pragma unroll
  for (int c = 0; c < 4; ++c)
#pragma unroll
    for (int reg = 0; reg < 4; ++reg) {
      int m = m0 + lq * 4 + reg;
      int n = nh * 256 + (w * 4 + c) * 16 + lm;
      float v = acc[c][reg];
      if (bias) v += bias[n];
      C[m * 512 + n] = v;
    }
}

// ---- fused: tmp = r_inte@W_SF.T ; tsum = sum_l tanh(c_slot + tmp) ----
__global__ __launch_bounds__(256) void k_tsum(const float* __restrict__ r_inte,
                                              const float* __restrict__ W_SF,
                                              const float* __restrict__ c_slot,
                                              float* __restrict__ tsum) {
  int idx = blockIdx.x * 256 + threadIdx.x;  // 8192
  int b = idx >> 9, hh = idx & 511;
  const float4* a = (const float4*)(r_inte + b * 512);
  const float4* wr = (const float4*)(W_SF + hh * 512);
  float acc = 0.f;
  for (int k = 0; k < 128; ++k) {
    float4 av = a[k], wv = wr[k];
    acc += av.x * wv.x + av.y * wv.y + av.z * wv.z + av.w * wv.w;
  }
  float s = 0.f;
  const float* cp = c_slot + b * 64 * 512 + hh;
  for (int l = 0; l < 64; ++l) s += ftanh(cp[l * 512] + acc);
  tsum[idx] = s;
}

// fbuf = tsum @ V_SF.T
__global__ __launch_bounds__(256) void k_fb(const float* __restrict__ tsum,
                                            const float* __restrict__ V_SF,
                                            float* __restrict__ fbuf) {
  int idx = blockIdx.x * 256 + threadIdx.x;  // 8192
  int b = idx >> 9, n = idx & 511;
  const float4* a = (const float4*)(tsum + b * 512);
  const float4* wr = (const float4*)(V_SF + n * 512);
  float acc = 0.f;
  for (int k = 0; k < 128; ++k) {
    float4 av = a[k], wv = wr[k];
    acc += av.x * wv.x + av.y * wv.y + av.z * wv.z + av.w * wv.w;
  }
  fbuf[idx] = acc;
}

// r_slot = fbuf (broadcast over l) * c_slot ; also zero smat
__global__ __launch_bounds__(256) void k_rslotz(const float* __restrict__ fbuf,
                                                const float* __restrict__ c_slot,
                                                float* __restrict__ r_slot,
                                                float* __restrict__ smat) {
  int idx = blockIdx.x * 256 + threadIdx.x;  // 524288
  int b = idx >> 15, hh = idx & 511;
  r_slot[idx] = fbuf[(b << 9) | hh] * c_slot[idx];
  if (idx < 4096) smat[idx] = 0.f;
}

// ---- dominant kernel ----
// smat[i,j] += sum_{b,g} exp( sum_h tanh(hid[b,i,h]+sf[b,j,h]) * W_ID[g,h] )
// grid (i=64, b=16); block 256 = 4 waves; wave w owns ntiles w*8..w*8+7 (128 g).
// A tile (64 j x 32 k) tanh'ed once into LDS; B fragments straight from L2.
__global__ __launch_bounds__(256) void k_score(const float* __restrict__ hid,
                                               const float* __restrict__ sf,
                                               const short* __restrict__ wbp,
                                               float* __restrict__ smat) {
  __shared__ short As[4 * 64 * 8];  // 4 KB
  __shared__ float red[4][64];
  const int i = blockIdx.x, b = blockIdx.y;
  const int t = threadIdx.x;
  const int w = t >> 6, lane = t & 63;
  const int lq = lane >> 4, lm = lane & 15;

  f32x4 acc[4][8];
#pragma unroll
  for (int r = 0; r < 4; ++r)
#pragma unroll
    for (int c = 0; c < 8; ++c) acc[r][c] = (f32x4){0.f, 0.f, 0.f, 0.f};

  const float* hrow = hid + (b * 64 + i) * 512;
  const float* sfb = sf + b * 64 * 512;
  const int am = (t >> 6) * 16 + (t & 15);  // j row staged by this thread
  const int ak = ((t >> 4) & 3) * 8;        // k offset within K-tile

  for (int ks = 0; ks < 16; ++ks) {
    const int k0 = ks * 32;
    const float* hp = hrow + k0 + ak;
    const float* sp = sfb + am * 512 + k0 + ak;
    float4 h0 = *(const float4*)hp;
    float4 h1 = *(const float4*)(hp + 4);
    float4 s0 = *(const float4*)sp;
    float4 s1 = *(const float4*)(sp + 4);
    bf16x8 av;
    av[0] = f2bf(ftanh(h0.x + s0.x));
    av[1] = f2bf(ftanh(h0.y + s0.y));
    av[2] = f2bf(ftanh(h0.z + s0.z));
    av[3] = f2bf(ftanh(h0.w + s0.w));
    av[4] = f2bf(ftanh(h1.x + s1.x));
    av[5] = f2bf(ftanh(h1.y + s1.y));
    av[6] = f2bf(ftanh(h1.z + s1.z));
    av[7] = f2bf(ftanh(h1.w + s1.w));
    __syncthreads();  // WAR on As
    *((bf16x8*)&As[t * 8]) = av;
    __syncthreads();
    bf16x8 af[4];
#pragma unroll
    for (int r = 0; r < 4; ++r) af[r] = *((const bf16x8*)&As[(r * 64 + lane) * 8]);
    const bf16x8* gb = (const bf16x8*)wbp + (ks * 32 + w * 8) * 64 + lane;
#pragma unroll
    for (int c = 0; c < 8; ++c) {
      bf16x8 bv = gb[c * 64];
#pragma unroll
      for (int r = 0; r < 4; ++r)
        acc[r][c] = __builtin_amdgcn_mfma_f32_16x16x32_bf16(af[r], bv, acc[r][c], 0, 0, 0);
    }
  }

  // exp + reduce over g (cols). C/D: col=lm, row=lq*4+reg within 16x16 tile.
#pragma unroll
  for (int r = 0; r < 4; ++r) {
#pragma unroll
    for (int reg = 0; reg < 4; ++reg) {
      float v = 0.f;
#pragma unroll
      for (int c = 0; c < 8; ++c) v += __expf(acc[r][c][reg]);
      v += __shfl_down(v, 8, 16);
      v += __shfl_down(v, 4, 16);
      v += __shfl_down(v, 2, 16);
      v += __shfl_down(v, 1, 16);
      if (lm == 0) red[w][r * 16 + lq * 4 + reg] = v;
    }
  }
  __syncthreads();
  if (t < 64) {
    float s = red[0][t] + red[1][t] + red[2][t] + red[3][t];
    atomicAdd(&smat[i * 64 + t], s);
  }
}

// ---- atts (recomputed per block from smat) + r_inte update ----
__global__ __launch_bounds__(256) void k_rinte(const float* __restrict__ smat,
                                               const float* __restrict__ r_slot,
                                               const float* __restrict__ c_inte,
                                               float* __restrict__ r_inte) {
  __shared__ float atts[64];
  const int t = threadIdx.x;
  if (t < 64) {
    float s = 0.f;
    for (int j = 0; j < 64; ++j) s += smat[t * 64 + j];
    atts[t] = smat[t * 65] / s;
  }
  __syncthreads();
  int idx = blockIdx.x * 256 + t;  // 8192
  int b = idx >> 9, hh = idx & 511;
  float acc = 0.f;
  for (int i2 = 0; i2 < 64; ++i2) acc += atts[i2] * r_slot[(b * 64 + i2) * 512 + hh];
  r_inte[idx] = acc + c_inte[idx];
}

// intent[b,n] = [r_inte[b], h[b,63]] @ W[n,:]
__global__ __launch_bounds__(256) void k_intent(const float* __restrict__ r_inte,
                                                const float* __restrict__ h,
                                                const float* __restrict__ W,
                                                float* __restrict__ out) {
  int idx = blockIdx.x * 256 + threadIdx.x;  // 1024
  int b = idx >> 6, n = idx & 63;
  const float4* w0 = (const float4*)(W + n * 1024);
  const float4* r = (const float4*)(r_inte + b * 512);
  const float4* hl = (const float4*)(h + (b * 64 + 63) * 512);
  float acc = 0.f;
  for (int k = 0; k < 128; ++k) {
    float4 a = r[k], wv = w0[k];
    acc += a.x * wv.x + a.y * wv.y + a.z * wv.z + a.w * wv.w;
  }
  for (int k = 0; k < 128; ++k) {
    float4 a = hl[k], wv = w0[128 + k];
    acc += a.x * wv.x + a.y * wv.y + a.z * wv.z + a.w * wv.w;
  }
  out[idx] = acc;
}

// slot[(b,l),n] = [h[b,l], r_slot[b,l]] @ W[n,:]
__global__ __launch_bounds__(256) void k_slot(const float* __restrict__ h,
                                              const float* __restrict__ r_slot,
                                              const float* __restrict__ W,
                                              float* __restrict__ out) {
  int idx = blockIdx.x * 256 + threadIdx.x;  // 65536
  int ml = idx >> 6, n = idx & 63;
  const float4* w0 = (const float4*)(W + n * 1024);
  const float4* hh = (const float4*)(h + ml * 512);
  const float4* rs = (const float4*)(r_slot + ml * 512);
  float acc = 0.f;
  for (int k = 0; k < 128; ++k) {
    float4 a = hh[k], wv = w0[k];
    acc += a.x * wv.x + a.y * wv.y + a.z * wv.z + a.w * wv.w;
  }
  for (int k = 0; k < 128; ++k) {
    float4 a = rs[k], wv = w0[128 + k];
    acc += a.x * wv.x + a.y * wv.y + a.z * wv.z + a.w * wv.w;
  }
  out[idx] = acc;
}

extern "C" void kernel_launch(void* const* d_in, const int* in_sizes, int n_in,
                              void* d_out, int out_size, void* d_ws, size_t ws_size,
                              hipStream_t stream) {
  const float* h      = (const float*)d_in[0];
  const float* c_slot = (const float*)d_in[1];
  const float* c_inte = (const float*)d_in[2];
  const float* W_SF   = (const float*)d_in[3];
  const float* V_SF   = (const float*)d_in[4];
  const float* V1_ID  = (const float*)d_in[5];
  const float* V2_w   = (const float*)d_in[6];
  const float* V2_b   = (const float*)d_in[7];
  const float* W_ID   = (const float*)d_in[8];
  const float* W_ia   = (const float*)d_in[9];
  const float* W_sa   = (const float*)d_in[10];
  float* out = (float*)d_out;

  float* ws     = (float*)d_ws;
  short* wbp    = (short*)ws;           // 131072 f
  short* vh     = (short*)(ws + 131072);
  short* vl     = (short*)(ws + 262144);
  float* sfbuf  = ws + 393216;   // 524288
  float* r_slot = ws + 917504;   // 524288
  float* hid    = ws + 1441792;  // 524288
  float* tsum   = ws + 1966080;  // 8192
  float* fbuf   = ws + 1974272;  // 8192
  float* r_inte = ws + 1982464;  // 8192
  float* smat   = ws + 1990656;  // 4096

  k_pack<<<1024, 256, 0, stream>>>(W_ID, wbp);
  k_packv<<<1024, 256, 0, stream>>>(V2_w, vh, vl);
  k_lin<<<dim3(64, 2), 256, 0, stream>>>(h, vh, vl, V2_b, sfbuf);
  k_packv<<<1024, 256, 0, stream>>>(V1_ID, vh, vl);  // reuse buffers for V1
  k_copy<<<32, 256, 0, stream>>>(c_inte, r_inte, 8192);

  for (int it = 0; it < 3; ++it) {
    k_tsum<<<32, 256, 0, stream>>>(r_inte, W_SF, c_slot, tsum);
    k_fb<<<32, 256, 0, stream>>>(tsum, V_SF, fbuf);
    k_rslotz<<<2048, 256, 0, stream>>>(fbuf, c_slot, r_slot, smat);
    k_lin<<<dim3(64, 2), 256, 0, stream>>>(r_slot, vh, vl, nullptr, hid);
    k_score<<<dim3(64, 16), 256, 0, stream>>>(hid, sfbuf, wbp, smat);
    k_rinte<<<32, 256, 0, stream>>>(smat, r_slot, c_inte, r_inte);
  }

  k_intent<<<4, 256, 0, stream>>>(r_inte, h, W_ia, out);
  k_slot<<<256, 256, 0, stream>>>(h, r_slot, W_sa, out + 1024);
}

// Round 5
// 555.352 us; speedup vs baseline: 4.4935x; 1.3032x over previous
//
#include <hip/hip_runtime.h>
#include <math.h>

// B=16, L=64, H=512, N_LABELS=64, ITERS=3
//
// ws layout (float offsets) — identical footprint to round 4 (passed):
//   wbp  [131072] W_ID bf16 B-fragment-major:
//        flat = ((kstep*32 + ntile)*64 + lane)*8 + j
//        g = ntile*16 + (lane&15); h = kstep*32 + (lane>>4)*8 + j
//   vh,vl [131072 each] split-bf16 pack (V2_w first, then V1_ID)
//   sfbuf/r_slot/hid [524288 each]
//   tsum/r_inte [8192 each], smat [4096]

typedef __attribute__((ext_vector_type(8))) short bf16x8;
typedef __attribute__((ext_vector_type(4))) float f32x4;

__device__ inline short f2bf(float x) {
  unsigned u = __float_as_uint(x);
  unsigned r = (u + 0x7fffu + ((u >> 16) & 1u)) >> 16;
  return (short)r;
}
__device__ inline float bf2f(short s) {
  return __uint_as_float(((unsigned)(unsigned short)s) << 16);
}
// tanh(x) = 1 - 2/(exp(2x)+1); saturates correctly at +/-inf.
__device__ inline float ftanh(float x) {
  float t = __expf(2.f * x);
  return 1.f - 2.f * __builtin_amdgcn_rcpf(t + 1.f);
}

// ---- prep: pack W_ID (bf16) + V2 (split bf16) + copy r_inte ----
__global__ __launch_bounds__(256) void k_prep1(const float* __restrict__ W_ID,
                                               const float* __restrict__ V2,
                                               const float* __restrict__ c_inte,
                                               short* __restrict__ wbp,
                                               short* __restrict__ dh,
                                               short* __restrict__ dl,
                                               float* __restrict__ r_inte) {
  int idx = blockIdx.x * 256 + threadIdx.x;  // 262144
  int j = idx & 7, lane = (idx >> 3) & 63;
  int ntile = (idx >> 9) & 31, kstep = idx >> 14;
  int g = ntile * 16 + (lane & 15);
  int h = kstep * 32 + (lane >> 4) * 8 + j;
  int src = g * 512 + h;
  wbp[idx] = f2bf(W_ID[src]);
  float x = V2[src];
  short hi = f2bf(x);
  dh[idx] = hi;
  dl[idx] = f2bf(x - bf2f(hi));
  if (idx < 8192) r_inte[idx] = c_inte[idx];
}

// pack V1 into vh/vl (after sfbuf GEMM consumed V2 pack)
__global__ __launch_bounds__(256) void k_prep2(const float* __restrict__ W,
                                               short* __restrict__ dh,
                                               short* __restrict__ dl) {
  int idx = blockIdx.x * 256 + threadIdx.x;  // 262144
  int j = idx & 7, lane = (idx >> 3) & 63;
  int ntile = (idx >> 9) & 31, kstep = idx >> 14;
  int g = ntile * 16 + (lane & 15);
  int h = kstep * 32 + (lane >> 4) * 8 + j;
  float x = W[g * 512 + h];
  short hi = f2bf(x);
  dh[idx] = hi;
  dl[idx] = f2bf(x - bf2f(hi));
}

// ---- split-precision MFMA linear: C[M,512] = A[M,512] @ W[512,512]^T (+bias)
// grid (M/16, 2); block 256 = 4 waves; wave w owns ntiles nh*16 + w*4 + c.
// B fragments direct from L2 (no cross-wave reuse), prefetched at loop top.
// A tile double-buffered in LDS, single barrier per kstep.
__global__ __launch_bounds__(256) void k_lin(const float* __restrict__ A,
                                             const short* __restrict__ bh,
                                             const short* __restrict__ bl,
                                             const float* __restrict__ bias,
                                             float* __restrict__ C) {
  __shared__ short Ah[2][512], Al[2][512];
  const int m0 = blockIdx.x * 16;
  const int nh = blockIdx.y;
  const int t = threadIdx.x;
  const int w = t >> 6, lane = t & 63;
  const int lq = lane >> 4, lm = lane & 15;
  f32x4 acc[4];
#pragma unroll
  for (int c = 0; c < 4; ++c) acc[c] = (f32x4){0.f, 0.f, 0.f, 0.f};

  const bf16x8* gbh = (const bf16x8*)bh + (nh * 16 + w * 4) * 64 + lane;
  const bf16x8* gbl = (const bf16x8*)bl + (nh * 16 + w * 4) * 64 + lane;

  // A staging: thread t handles fragment positions t*2, t*2+1
  const int la = t >> 2, j0 = (t & 3) * 2;
  const int m = la & 15, kk = (la >> 4) * 8 + j0;
  const float* abase = A + (m0 + m) * 512 + kk;

  for (int ks = 0; ks < 16; ++ks) {
    const int buf = ks & 1;
    // prefetch B (8 loads in flight during A staging)
    bf16x8 b0h = gbh[ks * 2048];
    bf16x8 b1h = gbh[ks * 2048 + 64];
    bf16x8 b2h = gbh[ks * 2048 + 128];
    bf16x8 b3h = gbh[ks * 2048 + 192];
    bf16x8 b0l = gbl[ks * 2048];
    bf16x8 b1l = gbl[ks * 2048 + 64];
    bf16x8 b2l = gbl[ks * 2048 + 128];
    bf16x8 b3l = gbl[ks * 2048 + 192];
    // stage A hi/lo
    float2 x = *(const float2*)(abase + ks * 32);
    short h0 = f2bf(x.x), h1 = f2bf(x.y);
    short l0 = f2bf(x.x - bf2f(h0)), l1 = f2bf(x.y - bf2f(h1));
    *(short2*)&Ah[buf][t * 2] = make_short2(h0, h1);
    *(short2*)&Al[buf][t * 2] = make_short2(l0, l1);
    __syncthreads();
    bf16x8 ah = *(const bf16x8*)&Ah[buf][lane * 8];
    bf16x8 al = *(const bf16x8*)&Al[buf][lane * 8];
    acc[0] = __builtin_amdgcn_mfma_f32_16x16x32_bf16(ah, b0h, acc[0], 0, 0, 0);
    acc[0] = __builtin_amdgcn_mfma_f32_16x16x32_bf16(al, b0h, acc[0], 0, 0, 0);
    acc[0] = __builtin_amdgcn_mfma_f32_16x16x32_bf16(ah, b0l, acc[0], 0, 0, 0);
    acc[1] = __builtin_amdgcn_mfma_f32_16x16x32_bf16(ah, b1h, acc[1], 0, 0, 0);
    acc[1] = __builtin_amdgcn_mfma_f32_16x16x32_bf16(al, b1h, acc[1], 0, 0, 0);
    acc[1] = __builtin_amdgcn_mfma_f32_16x16x32_bf16(ah, b1l, acc[1], 0, 0, 0);
    acc[2] = __builtin_amdgcn_mfma_f32_16x16x32_bf16(ah, b2h, acc[2], 0, 0, 0);
    acc[2] = __builtin_amdgcn_mfma_f32_16x16x32_bf16(al, b2h, acc[2], 0, 0, 0);
    acc[2] = __builtin_amdgcn_mfma_f32_16x16x32_bf16(ah, b2l, acc[2], 0, 0, 0);
    acc[3] = __builtin_amdgcn_mfma_f32_16x16x32_bf16(ah, b3h, acc[3], 0, 0, 0);
    acc[3] = __builtin_amdgcn_mfma_f32_16x16x32_bf16(al, b3h, acc[3], 0, 0, 0);
    acc[3] = __builtin_amdgcn_mfma_f32_16x16x32_bf16(ah, b3l, acc[3], 0, 0, 0);
  }
#pragma unroll
  for (int c = 0; c < 4; ++c)
#pragma unroll
    for (int reg = 0; reg < 4; ++reg) {
      int mm = m0 + lq * 4 + reg;
      int n = nh * 256 + (w * 4 + c) * 16 + lm;
      float v = acc[c][reg];
      if (bias) v += bias[n];
      C[mm * 512 + n] = v;
    }
}

// ---- fused: tmp = r_inte@W_SF.T ; tsum = sum_l tanh(c_slot + tmp) ----
__global__ __launch_bounds__(256) void k_tsum(const float* __restrict__ r_inte,
                                              const float* __restrict__ W_SF,
                                              const float* __restrict__ c_slot,
                                              float* __restrict__ tsum) {
  int idx = blockIdx.x * 256 + threadIdx.x;  // 8192
  int b = idx >> 9, hh = idx & 511;
  const float4* a = (const float4*)(r_inte + b * 512);
  const float4* wr = (const float4*)(W_SF + hh * 512);
  float acc = 0.f;
  for (int k = 0; k < 128; ++k) {
    float4 av = a[k], wv = wr[k];
    acc += av.x * wv.x + av.y * wv.y + av.z * wv.z + av.w * wv.w;
  }
  float s = 0.f;
  const float* cp = c_slot + b * 64 * 512 + hh;
  for (int l = 0; l < 64; ++l) s += ftanh(cp[l * 512] + acc);
  tsum[idx] = s;
}

// ---- fused: f = tsum@V_SF.T ; r_slot = f*c_slot ; zero smat ----
__global__ __launch_bounds__(256) void k_fbrz(const float* __restrict__ tsum,
                                              const float* __restrict__ V_SF,
                                              const float* __restrict__ c_slot,
                                              float* __restrict__ r_slot,
                                              float* __restrict__ smat) {
  int idx = blockIdx.x * 256 + threadIdx.x;  // 8192
  int b = idx >> 9, n = idx & 511;
  const float4* a = (const float4*)(tsum + b * 512);
  const float4* wr = (const float4*)(V_SF + n * 512);
  float acc = 0.f;
  for (int k = 0; k < 128; ++k) {
    float4 av = a[k], wv = wr[k];
    acc += av.x * wv.x + av.y * wv.y + av.z * wv.z + av.w * wv.w;
  }
  const float* cp = c_slot + b * 64 * 512 + n;
  float* rp = r_slot + b * 64 * 512 + n;
  for (int l = 0; l < 64; ++l) rp[l * 512] = acc * cp[l * 512];
  if (idx < 4096) smat[idx] = 0.f;
}

// ---- dominant kernel v3 ----
// smat[i,j] += sum_{b,g} exp( sum_h tanh(hid[b,i,h]+sf[b,j,h]) * W_ID[g,h] )
// grid (i=64, b=16, nh=2); block 256 = 4 waves; wave w owns ntiles nh*16+w*4+c.
// acc 64 regs/wave; B prefetched from L2 at loop top; A double-buffered, one
// barrier per kstep.
__global__ __launch_bounds__(256) void k_score(const float* __restrict__ hid,
                                               const float* __restrict__ sf,
                                               const short* __restrict__ wbp,
                                               float* __restrict__ smat) {
  __shared__ short As[2][2048];  // 8 KB
  __shared__ float red[4][64];
  const int i = blockIdx.x, b = blockIdx.y, nh = blockIdx.z;
  const int t = threadIdx.x;
  const int w = t >> 6, lane = t & 63;
  const int lq = lane >> 4, lm = lane & 15;

  f32x4 acc[4][4];
#pragma unroll
  for (int r = 0; r < 4; ++r)
#pragma unroll
    for (int c = 0; c < 4; ++c) acc[r][c] = (f32x4){0.f, 0.f, 0.f, 0.f};

  const float* hrow = hid + (b * 64 + i) * 512;
  const float* sfb = sf + b * 64 * 512;
  const int am = (t >> 6) * 16 + (t & 15);  // j row staged by this thread
  const int ak = ((t >> 4) & 3) * 8;        // k offset within K-tile

  const bf16x8* gb = (const bf16x8*)wbp + (nh * 16 + w * 4) * 64 + lane;

  for (int ks = 0; ks < 16; ++ks) {
    const int buf = ks & 1;
    // prefetch this kstep's B fragments (in flight during tanh staging)
    bf16x8 b0 = gb[ks * 2048];
    bf16x8 b1 = gb[ks * 2048 + 64];
    bf16x8 b2 = gb[ks * 2048 + 128];
    bf16x8 b3 = gb[ks * 2048 + 192];
    // stage A: tanh(hid + sf) -> bf16 fragment order
    const int k0 = ks * 32;
    const float* hp = hrow + k0 + ak;
    const float* sp = sfb + am * 512 + k0 + ak;
    float4 h0 = *(const float4*)hp;
    float4 h1 = *(const float4*)(hp + 4);
    float4 s0 = *(const float4*)sp;
    float4 s1 = *(const float4*)(sp + 4);
    bf16x8 av;
    av[0] = f2bf(ftanh(h0.x + s0.x));
    av[1] = f2bf(ftanh(h0.y + s0.y));
    av[2] = f2bf(ftanh(h0.z + s0.z));
    av[3] = f2bf(ftanh(h0.w + s0.w));
    av[4] = f2bf(ftanh(h1.x + s1.x));
    av[5] = f2bf(ftanh(h1.y + s1.y));
    av[6] = f2bf(ftanh(h1.z + s1.z));
    av[7] = f2bf(ftanh(h1.w + s1.w));
    *((bf16x8*)&As[buf][t * 8]) = av;
    __syncthreads();
    bf16x8 af0 = *(const bf16x8*)&As[buf][(0 * 64 + lane) * 8];
    bf16x8 af1 = *(const bf16x8*)&As[buf][(1 * 64 + lane) * 8];
    bf16x8 af2 = *(const bf16x8*)&As[buf][(2 * 64 + lane) * 8];
    bf16x8 af3 = *(const bf16x8*)&As[buf][(3 * 64 + lane) * 8];
    acc[0][0] = __builtin_amdgcn_mfma_f32_16x16x32_bf16(af0, b0, acc[0][0], 0, 0, 0);
    acc[1][0] = __builtin_amdgcn_mfma_f32_16x16x32_bf16(af1, b0, acc[1][0], 0, 0, 0);
    acc[2][0] = __builtin_amdgcn_mfma_f32_16x16x32_bf16(af2, b0, acc[2][0], 0, 0, 0);
    acc[3][0] = __builtin_amdgcn_mfma_f32_16x16x32_bf16(af3, b0, acc[3][0], 0, 0, 0);
    acc[0][1] = __builtin_amdgcn_mfma_f32_16x16x32_bf16(af0, b1, acc[0][1], 0, 0, 0);
    acc[1][1] = __builtin_amdgcn_mfma_f32_16x16x32_bf16(af1, b1, acc[1][1], 0, 0, 0);
    acc[2][1] = __builtin_amdgcn_mfma_f32_16x16x32_bf16(af2, b1, acc[2][1], 0, 0, 0);
    acc[3][1] = __builtin_amdgcn_mfma_f32_16x16x32_bf16(af3, b1, acc[3][1], 0, 0, 0);
    acc[0][2] = __builtin_amdgcn_mfma_f32_16x16x32_bf16(af0, b2, acc[0][2], 0, 0, 0);
    acc[1][2] = __builtin_amdgcn_mfma_f32_16x16x32_bf16(af1, b2, acc[1][2], 0, 0, 0);
    acc[2][2] = __builtin_amdgcn_mfma_f32_16x16x32_bf16(af2, b2, acc[2][2], 0, 0, 0);
    acc[3][2] = __builtin_amdgcn_mfma_f32_16x16x32_bf16(af3, b2, acc[3][2], 0, 0, 0);
    acc[0][3] = __builtin_amdgcn_mfma_f32_16x16x32_bf16(af0, b3, acc[0][3], 0, 0, 0);
    acc[1][3] = __builtin_amdgcn_mfma_f32_16x16x32_bf16(af1, b3, acc[1][3], 0, 0, 0);
    acc[2][3] = __builtin_amdgcn_mfma_f32_16x16x32_bf16(af2, b3, acc[2][3], 0, 0, 0);
    acc[3][3] = __builtin_amdgcn_mfma_f32_16x16x32_bf16(af3, b3, acc[3][3], 0, 0, 0);
  }

  // exp + reduce over g. C/D: col=lm, row=lq*4+reg within 16x16 tile.
#pragma unroll
  for (int r = 0; r < 4; ++r) {
#pragma unroll
    for (int reg = 0; reg < 4; ++reg) {
      float v = __expf(acc[r][0][reg]) + __expf(acc[r][1][reg]) +
                __expf(acc[r][2][reg]) + __expf(acc[r][3][reg]);
      v += __shfl_down(v, 8, 16);
      v += __shfl_down(v, 4, 16);
      v += __shfl_down(v, 2, 16);
      v += __shfl_down(v, 1, 16);
      if (lm == 0) red[w][r * 16 + lq * 4 + reg] = v;
    }
  }
  __syncthreads();
  if (t < 64) {
    float s = red[0][t] + red[1][t] + red[2][t] + red[3][t];
    atomicAdd(&smat[i * 64 + t], s);
  }
}

// ---- atts (recomputed per block from smat) + r_inte update ----
__global__ __launch_bounds__(256) void k_rinte(const float* __restrict__ smat,
                                               const float* __restrict__ r_slot,
                                               const float* __restrict__ c_inte,
                                               float* __restrict__ r_inte) {
  __shared__ float atts[64];
  const int t = threadIdx.x;
  if (t < 64) {
    float s = 0.f;
    for (int j = 0; j < 64; ++j) s += smat[t * 64 + j];
    atts[t] = smat[t * 65] / s;
  }
  __syncthreads();
  int idx = blockIdx.x * 256 + t;  // 8192
  int b = idx >> 9, hh = idx & 511;
  float acc = 0.f;
  for (int i2 = 0; i2 < 64; ++i2) acc += atts[i2] * r_slot[(b * 64 + i2) * 512 + hh];
  r_inte[idx] = acc + c_inte[idx];
}

// intent[b,n] = [r_inte[b], h[b,63]] @ W[n,:]
__global__ __launch_bounds__(256) void k_intent(const float* __restrict__ r_inte,
                                                const float* __restrict__ h,
                                                const float* __restrict__ W,
                                                float* __restrict__ out) {
  int idx = blockIdx.x * 256 + threadIdx.x;  // 1024
  int b = idx >> 6, n = idx & 63;
  const float4* w0 = (const float4*)(W + n * 1024);
  const float4* r = (const float4*)(r_inte + b * 512);
  const float4* hl = (const float4*)(h + (b * 64 + 63) * 512);
  float acc = 0.f;
  for (int k = 0; k < 128; ++k) {
    float4 a = r[k], wv = w0[k];
    acc += a.x * wv.x + a.y * wv.y + a.z * wv.z + a.w * wv.w;
  }
  for (int k = 0; k < 128; ++k) {
    float4 a = hl[k], wv = w0[128 + k];
    acc += a.x * wv.x + a.y * wv.y + a.z * wv.z + a.w * wv.w;
  }
  out[idx] = acc;
}

// slot[(b,l),n] = [h[b,l], r_slot[b,l]] @ W[n,:]
__global__ __launch_bounds__(256) void k_slot(const float* __restrict__ h,
                                              const float* __restrict__ r_slot,
                                              const float* __restrict__ W,
                                              float* __restrict__ out) {
  int idx = blockIdx.x * 256 + threadIdx.x;  // 65536
  int ml = idx >> 6, n = idx & 63;
  const float4* w0 = (const float4*)(W + n * 1024);
  const float4* hh = (const float4*)(h + ml * 512);
  const float4* rs = (const float4*)(r_slot + ml * 512);
  float acc = 0.f;
  for (int k = 0; k < 128; ++k) {
    float4 a = hh[k], wv = w0[k];
    acc += a.x * wv.x + a.y * wv.y + a.z * wv.z + a.w * wv.w;
  }
  for (int k = 0; k < 128; ++k) {
    float4 a = rs[k], wv = w0[128 + k];
    acc += a.x * wv.x + a.y * wv.y + a.z * wv.z + a.w * wv.w;
  }
  out[idx] = acc;
}

extern "C" void kernel_launch(void* const* d_in, const int* in_sizes, int n_in,
                              void* d_out, int out_size, void* d_ws, size_t ws_size,
                              hipStream_t stream) {
  const float* h      = (const float*)d_in[0];
  const float* c_slot = (const float*)d_in[1];
  const float* c_inte = (const float*)d_in[2];
  const float* W_SF   = (const float*)d_in[3];
  const float* V_SF   = (const float*)d_in[4];
  const float* V1_ID  = (const float*)d_in[5];
  const float* V2_w   = (const float*)d_in[6];
  const float* V2_b   = (const float*)d_in[7];
  const float* W_ID   = (const float*)d_in[8];
  const float* W_ia   = (const float*)d_in[9];
  const float* W_sa   = (const float*)d_in[10];
  float* out = (float*)d_out;

  float* ws     = (float*)d_ws;
  short* wbp    = (short*)ws;           // 131072 f
  short* vh     = (short*)(ws + 131072);
  short* vl     = (short*)(ws + 262144);
  float* sfbuf  = ws + 393216;   // 524288
  float* r_slot = ws + 917504;   // 524288
  float* hid    = ws + 1441792;  // 524288
  float* tsum   = ws + 1966080;  // 8192
  float* r_inte = ws + 1974272;  // 8192
  float* smat   = ws + 1982464;  // 4096

  k_prep1<<<1024, 256, 0, stream>>>(W_ID, V2_w, c_inte, wbp, vh, vl, r_inte);
  k_lin<<<dim3(64, 2), 256, 0, stream>>>(h, vh, vl, V2_b, sfbuf);
  k_prep2<<<1024, 256, 0, stream>>>(V1_ID, vh, vl);  // reuse buffers for V1

  for (int it = 0; it < 3; ++it) {
    k_tsum<<<32, 256, 0, stream>>>(r_inte, W_SF, c_slot, tsum);
    k_fbrz<<<32, 256, 0, stream>>>(tsum, V_SF, c_slot, r_slot, smat);
    k_lin<<<dim3(64, 2), 256, 0, stream>>>(r_slot, vh, vl, nullptr, hid);
    k_score<<<dim3(64, 16, 2), 256, 0, stream>>>(hid, sfbuf, wbp, smat);
    k_rinte<<<32, 256, 0, stream>>>(smat, r_slot, c_inte, r_inte);
  }

  k_intent<<<4, 256, 0, stream>>>(r_inte, h, W_ia, out);
  k_slot<<<256, 256, 0, stream>>>(h, r_slot, W_sa, out + 1024);
}

// Round 6
// 446.281 us; speedup vs baseline: 5.5917x; 1.2444x over previous
//
#include <hip/hip_runtime.h>
#include <math.h>

// B=16, L=64, H=512, N_LABELS=64, ITERS=3
//
// ws layout (float offsets):
//   wbp   0        [131072] W_ID bf16 B-fragment-major:
//         frag = (kstep*32 + ntile)*64 + lane; elem j:
//         g = ntile*16 + (lane&15); h = kstep*32 + (lane>>4)*8 + j
//   vh    131072, vl 262144 [131072 each] split-bf16 pack (V2 then V1)
//   sfbuf 393216, r_slot 917504, hid 1441792 [524288 each]
//   tsum 1966080, r_inte 1974272 [8192], smat 1982464 [4096]
//   wsf_t 1986560, vsf_t 2248704 [262144 each]  (transposed 512x512)
//   wia_t = hid+0, wsa_t = hid+65536 (transposed 1024x64; hid dead after loop)

typedef __attribute__((ext_vector_type(8))) short bf16x8;
typedef __attribute__((ext_vector_type(4))) float f32x4;

__device__ inline short f2bf(float x) {  // RNE (used for weights)
  unsigned u = __float_as_uint(x);
  unsigned r = (u + 0x7fffu + ((u >> 16) & 1u)) >> 16;
  return (short)r;
}
__device__ inline float bf2f(short s) {
  return __uint_as_float(((unsigned)(unsigned short)s) << 16);
}
// truncating pack of two floats -> two bf16 in one uint (cheap, for tanh vals)
__device__ inline unsigned pack2(float a, float b) {
  return (__float_as_uint(a) >> 16) | (__float_as_uint(b) & 0xffff0000u);
}
// tanh(x) = 1 - 2/(exp(2x)+1); saturates correctly at +/-inf.
__device__ inline float ftanh(float x) {
  float t = __expf(2.f * x);
  return 1.f - 2.f * __builtin_amdgcn_rcpf(t + 1.f);
}

// ---- prep: pack W_ID (bf16) + V2 (split bf16) + copy r_inte ----
__global__ __launch_bounds__(256) void k_prep1(const float* __restrict__ W_ID,
                                               const float* __restrict__ V2,
                                               const float* __restrict__ c_inte,
                                               short* __restrict__ wbp,
                                               short* __restrict__ dh,
                                               short* __restrict__ dl,
                                               float* __restrict__ r_inte) {
  int idx = blockIdx.x * 256 + threadIdx.x;  // 262144
  int j = idx & 7, lane = (idx >> 3) & 63;
  int ntile = (idx >> 9) & 31, kstep = idx >> 14;
  int g = ntile * 16 + (lane & 15);
  int h = kstep * 32 + (lane >> 4) * 8 + j;
  int src = g * 512 + h;
  wbp[idx] = f2bf(W_ID[src]);
  float x = V2[src];
  short hi = f2bf(x);
  dh[idx] = hi;
  dl[idx] = f2bf(x - bf2f(hi));
  if (idx < 8192) r_inte[idx] = c_inte[idx];
}

__global__ __launch_bounds__(256) void k_prep2(const float* __restrict__ W,
                                               short* __restrict__ dh,
                                               short* __restrict__ dl) {
  int idx = blockIdx.x * 256 + threadIdx.x;  // 262144
  int j = idx & 7, lane = (idx >> 3) & 63;
  int ntile = (idx >> 9) & 31, kstep = idx >> 14;
  int g = ntile * 16 + (lane & 15);
  int h = kstep * 32 + (lane >> 4) * 8 + j;
  float x = W[g * 512 + h];
  short hi = f2bf(x);
  dh[idx] = hi;
  dl[idx] = f2bf(x - bf2f(hi));
}

// ---- LDS-tiled transpose: out[C x R] = in[R x C]^T, 64x64 tiles ----
__global__ __launch_bounds__(256) void k_transp(const float* __restrict__ in,
                                                float* __restrict__ out,
                                                int R, int C) {
  __shared__ float tile[64][65];
  const int c0 = blockIdx.x * 64, r0 = blockIdx.y * 64;
  const int tx = threadIdx.x & 63, ty = threadIdx.x >> 6;
#pragma unroll
  for (int it = 0; it < 16; ++it) {
    int rl = ty + it * 4;
    tile[rl][tx] = in[(r0 + rl) * C + c0 + tx];
  }
  __syncthreads();
#pragma unroll
  for (int it = 0; it < 16; ++it) {
    int cl = ty + it * 4;
    out[(c0 + cl) * R + r0 + tx] = tile[tx][cl];
  }
}

// ---- split-precision MFMA linear: C[M,512] = A[M,512] @ W[512,512]^T (+bias)
__global__ __launch_bounds__(256) void k_lin(const float* __restrict__ A,
                                             const short* __restrict__ bh,
                                             const short* __restrict__ bl,
                                             const float* __restrict__ bias,
                                             float* __restrict__ C) {
  __shared__ short Ah[2][512], Al[2][512];
  const int m0 = blockIdx.x * 16;
  const int nh = blockIdx.y;
  const int t = threadIdx.x;
  const int w = t >> 6, lane = t & 63;
  const int lq = lane >> 4, lm = lane & 15;
  f32x4 acc[4];
#pragma unroll
  for (int c = 0; c < 4; ++c) acc[c] = (f32x4){0.f, 0.f, 0.f, 0.f};

  const bf16x8* gbh = (const bf16x8*)bh + (nh * 16 + w * 4) * 64 + lane;
  const bf16x8* gbl = (const bf16x8*)bl + (nh * 16 + w * 4) * 64 + lane;

  const int la = t >> 2, j0 = (t & 3) * 2;
  const int m = la & 15, kk = (la >> 4) * 8 + j0;
  const float* abase = A + (m0 + m) * 512 + kk;

  for (int ks = 0; ks < 16; ++ks) {
    const int buf = ks & 1;
    bf16x8 b0h = gbh[ks * 2048];
    bf16x8 b1h = gbh[ks * 2048 + 64];
    bf16x8 b2h = gbh[ks * 2048 + 128];
    bf16x8 b3h = gbh[ks * 2048 + 192];
    bf16x8 b0l = gbl[ks * 2048];
    bf16x8 b1l = gbl[ks * 2048 + 64];
    bf16x8 b2l = gbl[ks * 2048 + 128];
    bf16x8 b3l = gbl[ks * 2048 + 192];
    float2 x = *(const float2*)(abase + ks * 32);
    short h0 = f2bf(x.x), h1 = f2bf(x.y);
    short l0 = f2bf(x.x - bf2f(h0)), l1 = f2bf(x.y - bf2f(h1));
    *(short2*)&Ah[buf][t * 2] = make_short2(h0, h1);
    *(short2*)&Al[buf][t * 2] = make_short2(l0, l1);
    __syncthreads();
    bf16x8 ah = *(const bf16x8*)&Ah[buf][lane * 8];
    bf16x8 al = *(const bf16x8*)&Al[buf][lane * 8];
    acc[0] = __builtin_amdgcn_mfma_f32_16x16x32_bf16(ah, b0h, acc[0], 0, 0, 0);
    acc[0] = __builtin_amdgcn_mfma_f32_16x16x32_bf16(al, b0h, acc[0], 0, 0, 0);
    acc[0] = __builtin_amdgcn_mfma_f32_16x16x32_bf16(ah, b0l, acc[0], 0, 0, 0);
    acc[1] = __builtin_amdgcn_mfma_f32_16x16x32_bf16(ah, b1h, acc[1], 0, 0, 0);
    acc[1] = __builtin_amdgcn_mfma_f32_16x16x32_bf16(al, b1h, acc[1], 0, 0, 0);
    acc[1] = __builtin_amdgcn_mfma_f32_16x16x32_bf16(ah, b1l, acc[1], 0, 0, 0);
    acc[2] = __builtin_amdgcn_mfma_f32_16x16x32_bf16(ah, b2h, acc[2], 0, 0, 0);
    acc[2] = __builtin_amdgcn_mfma_f32_16x16x32_bf16(al, b2h, acc[2], 0, 0, 0);
    acc[2] = __builtin_amdgcn_mfma_f32_16x16x32_bf16(ah, b2l, acc[2], 0, 0, 0);
    acc[3] = __builtin_amdgcn_mfma_f32_16x16x32_bf16(ah, b3h, acc[3], 0, 0, 0);
    acc[3] = __builtin_amdgcn_mfma_f32_16x16x32_bf16(al, b3h, acc[3], 0, 0, 0);
    acc[3] = __builtin_amdgcn_mfma_f32_16x16x32_bf16(ah, b3l, acc[3], 0, 0, 0);
  }
#pragma unroll
  for (int c = 0; c < 4; ++c)
#pragma unroll
    for (int reg = 0; reg < 4; ++reg) {
      int mm = m0 + lq * 4 + reg;
      int n = nh * 256 + (w * 4 + c) * 16 + lm;
      float v = acc[c][reg];
      if (bias) v += bias[n];
      C[mm * 512 + n] = v;
    }
}

// ---- fused (coalesced): tmp = r_inte@W_SF.T via wsf_t; tsum = sum_l tanh ----
__global__ __launch_bounds__(256) void k_tsum(const float* __restrict__ r_inte,
                                              const float* __restrict__ wsf_t,
                                              const float* __restrict__ c_slot,
                                              float* __restrict__ tsum) {
  int idx = blockIdx.x * 256 + threadIdx.x;  // 8192
  int b = idx >> 9, hh = idx & 511;
  const float* rv = r_inte + b * 512;
  float acc = 0.f;
  for (int k = 0; k < 512; k += 4) {
    float4 x = *(const float4*)(rv + k);
    acc += x.x * wsf_t[k * 512 + hh] + x.y * wsf_t[(k + 1) * 512 + hh] +
           x.z * wsf_t[(k + 2) * 512 + hh] + x.w * wsf_t[(k + 3) * 512 + hh];
  }
  float s = 0.f;
  const float* cp = c_slot + b * 64 * 512 + hh;
  for (int l = 0; l < 64; ++l) s += ftanh(cp[l * 512] + acc);
  tsum[idx] = s;
}

// ---- fused (coalesced): f = tsum@V_SF.T via vsf_t; r_slot = f*c_slot; smat=0
__global__ __launch_bounds__(256) void k_fbrz(const float* __restrict__ tsum,
                                              const float* __restrict__ vsf_t,
                                              const float* __restrict__ c_slot,
                                              float* __restrict__ r_slot,
                                              float* __restrict__ smat) {
  int idx = blockIdx.x * 256 + threadIdx.x;  // 8192
  int b = idx >> 9, n = idx & 511;
  const float* tv = tsum + b * 512;
  float acc = 0.f;
  for (int k = 0; k < 512; k += 4) {
    float4 x = *(const float4*)(tv + k);
    acc += x.x * vsf_t[k * 512 + n] + x.y * vsf_t[(k + 1) * 512 + n] +
           x.z * vsf_t[(k + 2) * 512 + n] + x.w * vsf_t[(k + 3) * 512 + n];
  }
  const float* cp = c_slot + b * 64 * 512 + n;
  float* rp = r_slot + b * 64 * 512 + n;
  for (int l = 0; l < 64; ++l) rp[l * 512] = acc * cp[l * 512];
  if (idx < 4096) smat[idx] = 0.f;
}

// ---- dominant kernel v4: 512 threads, 8 waves, no tanh duplication ----
// smat[i,j] += sum_{b,g} exp( sum_h tanh(hid[b,i,h]+sf[b,j,h]) * W_ID[g,h] )
// grid (i=64, b=16); wave w owns ntiles w*4..w*4+3 (64 g); block covers 512 g.
__global__ __launch_bounds__(512, 4) void k_score(const float* __restrict__ hid,
                                                  const float* __restrict__ sf,
                                                  const short* __restrict__ wbp,
                                                  float* __restrict__ smat) {
  __shared__ short As[2][2048];  // 8 KB, A tile in fragment order
  __shared__ float red[8][64];
  const int i = blockIdx.x, b = blockIdx.y;
  const int t = threadIdx.x;
  const int w = t >> 6, lane = t & 63;
  const int lq = lane >> 4, lm = lane & 15;

  f32x4 acc[4][4];
#pragma unroll
  for (int r = 0; r < 4; ++r)
#pragma unroll
    for (int c = 0; c < 4; ++c) acc[r][c] = (f32x4){0.f, 0.f, 0.f, 0.f};

  const float* hrow = hid + (b * 64 + i) * 512;
  const float* sfb = sf + b * 64 * 512;

  // staging: thread t -> frag_id = t>>1 (mtile, lane), half = t&1 (4 elems)
  const int fid = t >> 1, half = t & 1;
  const int am = (fid >> 6) * 16 + (fid & 15);       // j row 0..63
  const int ak = ((fid >> 4) & 3) * 8 + half * 4;    // k offset in K-tile
  const int aoff = fid * 8 + half * 4;               // LDS short offset

  const bf16x8* gb = (const bf16x8*)wbp + (w * 4) * 64 + lane;

  for (int ks = 0; ks < 16; ++ks) {
    const int buf = ks & 1;
    // prefetch B fragments (L2) — consumed after the barrier
    bf16x8 b0 = gb[ks * 2048];
    bf16x8 b1 = gb[ks * 2048 + 64];
    bf16x8 b2 = gb[ks * 2048 + 128];
    bf16x8 b3 = gb[ks * 2048 + 192];
    // stage A: tanh(hid + sf) -> bf16 (truncate), fragment order
    const float* hp = hrow + ks * 32 + ak;
    const float* sp = sfb + am * 512 + ks * 32 + ak;
    float4 hv = *(const float4*)hp;
    float4 sv = *(const float4*)sp;
    float t0 = ftanh(hv.x + sv.x);
    float t1 = ftanh(hv.y + sv.y);
    float t2 = ftanh(hv.z + sv.z);
    float t3 = ftanh(hv.w + sv.w);
    uint2 pk;
    pk.x = pack2(t0, t1);
    pk.y = pack2(t2, t3);
    *(uint2*)&As[buf][aoff] = pk;
    __syncthreads();
    bf16x8 af0 = *(const bf16x8*)&As[buf][(0 * 64 + lane) * 8];
    bf16x8 af1 = *(const bf16x8*)&As[buf][(1 * 64 + lane) * 8];
    bf16x8 af2 = *(const bf16x8*)&As[buf][(2 * 64 + lane) * 8];
    bf16x8 af3 = *(const bf16x8*)&As[buf][(3 * 64 + lane) * 8];
    acc[0][0] = __builtin_amdgcn_mfma_f32_16x16x32_bf16(af0, b0, acc[0][0], 0, 0, 0);
    acc[1][0] = __builtin_amdgcn_mfma_f32_16x16x32_bf16(af1, b0, acc[1][0], 0, 0, 0);
    acc[2][0] = __builtin_amdgcn_mfma_f32_16x16x32_bf16(af2, b0, acc[2][0], 0, 0, 0);
    acc[3][0] = __builtin_amdgcn_mfma_f32_16x16x32_bf16(af3, b0, acc[3][0], 0, 0, 0);
    acc[0][1] = __builtin_amdgcn_mfma_f32_16x16x32_bf16(af0, b1, acc[0][1], 0, 0, 0);
    acc[1][1] = __builtin_amdgcn_mfma_f32_16x16x32_bf16(af1, b1, acc[1][1], 0, 0, 0);
    acc[2][1] = __builtin_amdgcn_mfma_f32_16x16x32_bf16(af2, b1, acc[2][1], 0, 0, 0);
    acc[3][1] = __builtin_amdgcn_mfma_f32_16x16x32_bf16(af3, b1, acc[3][1], 0, 0, 0);
    acc[0][2] = __builtin_amdgcn_mfma_f32_16x16x32_bf16(af0, b2, acc[0][2], 0, 0, 0);
    acc[1][2] = __builtin_amdgcn_mfma_f32_16x16x32_bf16(af1, b2, acc[1][2], 0, 0, 0);
    acc[2][2] = __builtin_amdgcn_mfma_f32_16x16x32_bf16(af2, b2, acc[2][2], 0, 0, 0);
    acc[3][2] = __builtin_amdgcn_mfma_f32_16x16x32_bf16(af3, b2, acc[3][2], 0, 0, 0);
    acc[0][3] = __builtin_amdgcn_mfma_f32_16x16x32_bf16(af0, b3, acc[0][3], 0, 0, 0);
    acc[1][3] = __builtin_amdgcn_mfma_f32_16x16x32_bf16(af1, b3, acc[1][3], 0, 0, 0);
    acc[2][3] = __builtin_amdgcn_mfma_f32_16x16x32_bf16(af2, b3, acc[2][3], 0, 0, 0);
    acc[3][3] = __builtin_amdgcn_mfma_f32_16x16x32_bf16(af3, b3, acc[3][3], 0, 0, 0);
  }

  // exp + reduce over g. C/D: col=lm, row=lq*4+reg within each 16x16 tile.
#pragma unroll
  for (int r = 0; r < 4; ++r) {
#pragma unroll
    for (int reg = 0; reg < 4; ++reg) {
      float v = __expf(acc[r][0][reg]) + __expf(acc[r][1][reg]) +
                __expf(acc[r][2][reg]) + __expf(acc[r][3][reg]);
      v += __shfl_down(v, 8, 16);
      v += __shfl_down(v, 4, 16);
      v += __shfl_down(v, 2, 16);
      v += __shfl_down(v, 1, 16);
      if (lm == 0) red[w][r * 16 + lq * 4 + reg] = v;
    }
  }
  __syncthreads();
  if (t < 64) {
    float s = 0.f;
#pragma unroll
    for (int ww = 0; ww < 8; ++ww) s += red[ww][t];
    atomicAdd(&smat[i * 64 + t], s);
  }
}

// ---- atts (recomputed per block from smat) + r_inte update ----
__global__ __launch_bounds__(256) void k_rinte(const float* __restrict__ smat,
                                               const float* __restrict__ r_slot,
                                               const float* __restrict__ c_inte,
                                               float* __restrict__ r_inte) {
  __shared__ float atts[64];
  const int t = threadIdx.x;
  if (t < 64) {
    float s = 0.f;
    for (int j = 0; j < 64; ++j) s += smat[t * 64 + j];
    atts[t] = smat[t * 65] / s;
  }
  __syncthreads();
  int idx = blockIdx.x * 256 + t;  // 8192
  int b = idx >> 9, hh = idx & 511;
  float acc = 0.f;
  for (int i2 = 0; i2 < 64; ++i2) acc += atts[i2] * r_slot[(b * 64 + i2) * 512 + hh];
  r_inte[idx] = acc + c_inte[idx];
}

// intent[b,n] = [r_inte[b], h[b,63]] @ W_ia[n,:]  via wia_t (coalesced)
__global__ __launch_bounds__(256) void k_intent(const float* __restrict__ r_inte,
                                                const float* __restrict__ h,
                                                const float* __restrict__ wia_t,
                                                float* __restrict__ out) {
  int idx = blockIdx.x * 256 + threadIdx.x;  // 1024
  int b = idx >> 6, n = idx & 63;
  const float* x1 = r_inte + b * 512;
  const float* x2 = h + (b * 64 + 63) * 512;
  float acc = 0.f;
  for (int k = 0; k < 512; k += 4) {
    float4 x = *(const float4*)(x1 + k);
    acc += x.x * wia_t[k * 64 + n] + x.y * wia_t[(k + 1) * 64 + n] +
           x.z * wia_t[(k + 2) * 64 + n] + x.w * wia_t[(k + 3) * 64 + n];
  }
  for (int k = 0; k < 512; k += 4) {
    float4 x = *(const float4*)(x2 + k);
    acc += x.x * wia_t[(512 + k) * 64 + n] + x.y * wia_t[(513 + k) * 64 + n] +
           x.z * wia_t[(514 + k) * 64 + n] + x.w * wia_t[(515 + k) * 64 + n];
  }
  out[idx] = acc;
}

// slot[(b,l),n] = [h[b,l], r_slot[b,l]] @ W_sa[n,:]  via wsa_t (coalesced)
__global__ __launch_bounds__(256) void k_slot(const float* __restrict__ h,
                                              const float* __restrict__ r_slot,
                                              const float* __restrict__ wsa_t,
                                              float* __restrict__ out) {
  int idx = blockIdx.x * 256 + threadIdx.x;  // 65536
  int ml = idx >> 6, n = idx & 63;
  const float* x1 = h + ml * 512;
  const float* x2 = r_slot + ml * 512;
  float acc = 0.f;
  for (int k = 0; k < 512; k += 4) {
    float4 x = *(const float4*)(x1 + k);
    acc += x.x * wsa_t[k * 64 + n] + x.y * wsa_t[(k + 1) * 64 + n] +
           x.z * wsa_t[(k + 2) * 64 + n] + x.w * wsa_t[(k + 3) * 64 + n];
  }
  for (int k = 0; k < 512; k += 4) {
    float4 x = *(const float4*)(x2 + k);
    acc += x.x * wsa_t[(512 + k) * 64 + n] + x.y * wsa_t[(513 + k) * 64 + n] +
           x.z * wsa_t[(514 + k) * 64 + n] + x.w * wsa_t[(515 + k) * 64 + n];
  }
  out[idx] = acc;
}

extern "C" void kernel_launch(void* const* d_in, const int* in_sizes, int n_in,
                              void* d_out, int out_size, void* d_ws, size_t ws_size,
                              hipStream_t stream) {
  const float* h      = (const float*)d_in[0];
  const float* c_slot = (const float*)d_in[1];
  const float* c_inte = (const float*)d_in[2];
  const float* W_SF   = (const float*)d_in[3];
  const float* V_SF   = (const float*)d_in[4];
  const float* V1_ID  = (const float*)d_in[5];
  const float* V2_w   = (const float*)d_in[6];
  const float* V2_b   = (const float*)d_in[7];
  const float* W_ID   = (const float*)d_in[8];
  const float* W_ia   = (const float*)d_in[9];
  const float* W_sa   = (const float*)d_in[10];
  float* out = (float*)d_out;

  float* ws     = (float*)d_ws;
  short* wbp    = (short*)ws;           // 131072 f
  short* vh     = (short*)(ws + 131072);
  short* vl     = (short*)(ws + 262144);
  float* sfbuf  = ws + 393216;   // 524288
  float* r_slot = ws + 917504;   // 524288
  float* hid    = ws + 1441792;  // 524288
  float* tsum   = ws + 1966080;  // 8192
  float* r_inte = ws + 1974272;  // 8192
  float* smat   = ws + 1982464;  // 4096
  float* wsf_t  = ws + 1986560;  // 262144
  float* vsf_t  = ws + 2248704;  // 262144  (end: 2510848 f ~= 10 MB)
  float* wia_t  = hid;           // reuse: hid dead after last k_score
  float* wsa_t  = hid + 65536;

  k_prep1<<<1024, 256, 0, stream>>>(W_ID, V2_w, c_inte, wbp, vh, vl, r_inte);
  k_transp<<<dim3(8, 8), 256, 0, stream>>>(W_SF, wsf_t, 512, 512);
  k_transp<<<dim3(8, 8), 256, 0, stream>>>(V_SF, vsf_t, 512, 512);
  k_lin<<<dim3(64, 2), 256, 0, stream>>>(h, vh, vl, V2_b, sfbuf);
  k_prep2<<<1024, 256, 0, stream>>>(V1_ID, vh, vl);  // reuse buffers for V1

  for (int it = 0; it < 3; ++it) {
    k_tsum<<<32, 256, 0, stream>>>(r_inte, wsf_t, c_slot, tsum);
    k_fbrz<<<32, 256, 0, stream>>>(tsum, vsf_t, c_slot, r_slot, smat);
    k_lin<<<dim3(64, 2), 256, 0, stream>>>(r_slot, vh, vl, nullptr, hid);
    k_score<<<dim3(64, 16), 512, 0, stream>>>(hid, sfbuf, wbp, smat);
    k_rinte<<<32, 256, 0, stream>>>(smat, r_slot, c_inte, r_inte);
  }

  k_transp<<<dim3(16, 1), 256, 0, stream>>>(W_ia, wia_t, 64, 1024);
  k_transp<<<dim3(16, 1), 256, 0, stream>>>(W_sa, wsa_t, 64, 1024);
  k_intent<<<4, 256, 0, stream>>>(r_inte, h, wia_t, out);
  k_slot<<<256, 256, 0, stream>>>(h, r_slot, wsa_t, out + 1024);
}

// Round 7
// 416.579 us; speedup vs baseline: 5.9904x; 1.0713x over previous
//
#include <hip/hip_runtime.h>
#include <math.h>

// B=16, L=64, H=512, N_LABELS=64, ITERS=3
//
// ws layout (float offsets):
//   wbp    0        [131072] W_ID bf16 B-fragment-major:
//          frag = (kstep*32 + ntile)*64 + lane; elem j:
//          g = ntile*16 + (lane&15); h = kstep*32 + (lane>>4)*8 + j
//   v2h 131072, v2l 262144, v1h 393216, v1l 524288 [131072 each] split-bf16
//   sfbuf 655360, r_slot 1179648, hid 1703936 [524288 each]
//   smat 2228224 [4096]
//   wsf_t 2232320, vsf_t 2494464 [262144 each]
//   wia_t 2756608, wsa_t 2822144 [65536 each]   (end ~2.89M floats = 11.6 MB)

typedef __attribute__((ext_vector_type(8))) short bf16x8;
typedef __attribute__((ext_vector_type(4))) float f32x4;

__device__ inline short f2bf(float x) {  // RNE
  unsigned u = __float_as_uint(x);
  unsigned r = (u + 0x7fffu + ((u >> 16) & 1u)) >> 16;
  return (short)r;
}
__device__ inline float bf2f(short s) {
  return __uint_as_float(((unsigned)(unsigned short)s) << 16);
}
__device__ inline unsigned pack2(float a, float b) {  // truncating 2xbf16 pack
  return (__float_as_uint(a) >> 16) | (__float_as_uint(b) & 0xffff0000u);
}
// tanh(x) = 1 - 2/(exp(2x)+1); saturates correctly.
__device__ inline float ftanh(float x) {
  float t = __expf(2.f * x);
  return 1.f - 2.f * __builtin_amdgcn_rcpf(t + 1.f);
}

// ---- single prep kernel: all packs + all transposes ----
__global__ __launch_bounds__(256) void k_prep_all(
    const float* __restrict__ W_ID, const float* __restrict__ V2,
    const float* __restrict__ V1, const float* __restrict__ W_SF,
    const float* __restrict__ V_SF, const float* __restrict__ W_ia,
    const float* __restrict__ W_sa, short* __restrict__ wbp,
    short* __restrict__ v2h, short* __restrict__ v2l,
    short* __restrict__ v1h, short* __restrict__ v1l,
    float* __restrict__ wsf_t, float* __restrict__ vsf_t,
    float* __restrict__ wia_t, float* __restrict__ wsa_t) {
  const int bx = blockIdx.x;
  const int t = threadIdx.x;
  if (bx < 1024) {  // fragment-major packs
    int idx = bx * 256 + t;  // 262144
    int j = idx & 7, lane = (idx >> 3) & 63;
    int ntile = (idx >> 9) & 31, kstep = idx >> 14;
    int g = ntile * 16 + (lane & 15);
    int h = kstep * 32 + (lane >> 4) * 8 + j;
    int src = g * 512 + h;
    wbp[idx] = f2bf(W_ID[src]);
    float x2 = V2[src];
    short h2 = f2bf(x2);
    v2h[idx] = h2;
    v2l[idx] = f2bf(x2 - bf2f(h2));
    float x1 = V1[src];
    short h1 = f2bf(x1);
    v1h[idx] = h1;
    v1l[idx] = f2bf(x1 - bf2f(h1));
  } else {  // transposes
    const float* tin;
    float* tout;
    int R, C, c0, r0;
    if (bx < 1088) {
      int bxx = bx - 1024;
      tin = W_SF; tout = wsf_t; R = 512; C = 512;
      c0 = (bxx & 7) * 64; r0 = (bxx >> 3) * 64;
    } else if (bx < 1152) {
      int bxx = bx - 1088;
      tin = V_SF; tout = vsf_t; R = 512; C = 512;
      c0 = (bxx & 7) * 64; r0 = (bxx >> 3) * 64;
    } else if (bx < 1168) {
      int bxx = bx - 1152;
      tin = W_ia; tout = wia_t; R = 64; C = 1024;
      c0 = bxx * 64; r0 = 0;
    } else {
      int bxx = bx - 1168;
      tin = W_sa; tout = wsa_t; R = 64; C = 1024;
      c0 = bxx * 64; r0 = 0;
    }
    __shared__ float tile[64][65];
    const int tx = t & 63, ty = t >> 6;
#pragma unroll
    for (int it2 = 0; it2 < 16; ++it2) {
      int rl = ty + it2 * 4;
      tile[rl][tx] = tin[(r0 + rl) * C + c0 + tx];
    }
    __syncthreads();
#pragma unroll
    for (int it2 = 0; it2 < 16; ++it2) {
      int cl = ty + it2 * 4;
      tout[(c0 + cl) * R + r0 + tx] = tile[tx][cl];
    }
  }
}

// ---- split-precision MFMA linear: C[M,512] = A[M,512] @ W[512,512]^T (+bias)
// Optionally zeroes smat (4096 f) with spare blocks.
__global__ __launch_bounds__(256) void k_lin(const float* __restrict__ A,
                                             const short* __restrict__ bh,
                                             const short* __restrict__ bl,
                                             const float* __restrict__ bias,
                                             float* __restrict__ C,
                                             float* __restrict__ smat0) {
  __shared__ short Ah[2][512], Al[2][512];
  const int m0 = blockIdx.x * 16;
  const int nh = blockIdx.y;
  const int t = threadIdx.x;
  if (smat0 && nh == 0 && blockIdx.x < 8) {
    smat0[blockIdx.x * 512 + t] = 0.f;
    smat0[blockIdx.x * 512 + 256 + t] = 0.f;
  }
  const int w = t >> 6, lane = t & 63;
  const int lq = lane >> 4, lm = lane & 15;
  f32x4 acc[4];
#pragma unroll
  for (int c = 0; c < 4; ++c) acc[c] = (f32x4){0.f, 0.f, 0.f, 0.f};

  const bf16x8* gbh = (const bf16x8*)bh + (nh * 16 + w * 4) * 64 + lane;
  const bf16x8* gbl = (const bf16x8*)bl + (nh * 16 + w * 4) * 64 + lane;

  const int la = t >> 2, j0 = (t & 3) * 2;
  const int m = la & 15, kk = (la >> 4) * 8 + j0;
  const float* abase = A + (m0 + m) * 512 + kk;

  for (int ks = 0; ks < 16; ++ks) {
    const int buf = ks & 1;
    bf16x8 b0h = gbh[ks * 2048];
    bf16x8 b1h = gbh[ks * 2048 + 64];
    bf16x8 b2h = gbh[ks * 2048 + 128];
    bf16x8 b3h = gbh[ks * 2048 + 192];
    bf16x8 b0l = gbl[ks * 2048];
    bf16x8 b1l = gbl[ks * 2048 + 64];
    bf16x8 b2l = gbl[ks * 2048 + 128];
    bf16x8 b3l = gbl[ks * 2048 + 192];
    float2 x = *(const float2*)(abase + ks * 32);
    short h0 = f2bf(x.x), h1 = f2bf(x.y);
    short l0 = f2bf(x.x - bf2f(h0)), l1 = f2bf(x.y - bf2f(h1));
    *(short2*)&Ah[buf][t * 2] = make_short2(h0, h1);
    *(short2*)&Al[buf][t * 2] = make_short2(l0, l1);
    __syncthreads();
    bf16x8 ah = *(const bf16x8*)&Ah[buf][lane * 8];
    bf16x8 al = *(const bf16x8*)&Al[buf][lane * 8];
    acc[0] = __builtin_amdgcn_mfma_f32_16x16x32_bf16(ah, b0h, acc[0], 0, 0, 0);
    acc[0] = __builtin_amdgcn_mfma_f32_16x16x32_bf16(al, b0h, acc[0], 0, 0, 0);
    acc[0] = __builtin_amdgcn_mfma_f32_16x16x32_bf16(ah, b0l, acc[0], 0, 0, 0);
    acc[1] = __builtin_amdgcn_mfma_f32_16x16x32_bf16(ah, b1h, acc[1], 0, 0, 0);
    acc[1] = __builtin_amdgcn_mfma_f32_16x16x32_bf16(al, b1h, acc[1], 0, 0, 0);
    acc[1] = __builtin_amdgcn_mfma_f32_16x16x32_bf16(ah, b1l, acc[1], 0, 0, 0);
    acc[2] = __builtin_amdgcn_mfma_f32_16x16x32_bf16(ah, b2h, acc[2], 0, 0, 0);
    acc[2] = __builtin_amdgcn_mfma_f32_16x16x32_bf16(al, b2h, acc[2], 0, 0, 0);
    acc[2] = __builtin_amdgcn_mfma_f32_16x16x32_bf16(ah, b2l, acc[2], 0, 0, 0);
    acc[3] = __builtin_amdgcn_mfma_f32_16x16x32_bf16(ah, b3h, acc[3], 0, 0, 0);
    acc[3] = __builtin_amdgcn_mfma_f32_16x16x32_bf16(al, b3h, acc[3], 0, 0, 0);
    acc[3] = __builtin_amdgcn_mfma_f32_16x16x32_bf16(ah, b3l, acc[3], 0, 0, 0);
  }
#pragma unroll
  for (int c = 0; c < 4; ++c)
#pragma unroll
    for (int reg = 0; reg < 4; ++reg) {
      int mm = m0 + lq * 4 + reg;
      int n = nh * 256 + (w * 4 + c) * 16 + lm;
      float v = acc[c][reg];
      if (bias) v += bias[n];
      C[mm * 512 + n] = v;
    }
}

// ---- fused per-iteration tail: atts + r_inte(LDS) + tmp GEMV + tanh-sum +
//      f GEMV + r_slot write.  grid 16 (b), 1024 threads.
__global__ __launch_bounds__(1024) void k_fused1(int first,
                                                 const float* __restrict__ smat,
                                                 float* __restrict__ r_slot,
                                                 const float* __restrict__ c_inte,
                                                 const float* __restrict__ c_slot,
                                                 const float* __restrict__ wsf_t,
                                                 const float* __restrict__ vsf_t) {
  __shared__ float riv[512];   // r_inte row
  __shared__ float va[512];    // tsum row
  __shared__ float red2[1024];
  __shared__ float av[64];
  const int b = blockIdx.x;
  const int t = threadIdx.x;
  const int h = t & 511, half = t >> 9;

  if (first) {
    if (t < 512) riv[t] = c_inte[b * 512 + t];
    __syncthreads();
  } else {
    // atts from smat: waves 0..3, wave w handles rows w*16..w*16+15
    if (t < 256) {
      const int w = t >> 6, lane = t & 63;
      for (int r = w * 16; r < w * 16 + 16; ++r) {
        float v = smat[r * 64 + lane];
        float s = v;
        s += __shfl_xor(s, 1);
        s += __shfl_xor(s, 2);
        s += __shfl_xor(s, 4);
        s += __shfl_xor(s, 8);
        s += __shfl_xor(s, 16);
        s += __shfl_xor(s, 32);
        float d = __shfl(v, r);  // diagonal element (col==row)
        if (lane == 0) av[r] = d / s;
      }
    }
    __syncthreads();
    // riv[h] = c_inte + sum_i av[i]*r_slot[b,i,h]  (2-way split over i)
    float a = 0.f;
    const float* rp = r_slot + (b * 64 + half * 32) * 512 + h;
    for (int i = 0; i < 32; ++i) a += av[half * 32 + i] * rp[i * 512];
    red2[t] = a;
    __syncthreads();
    if (t < 512) riv[t] = red2[t] + red2[t + 512] + c_inte[b * 512 + t];
    __syncthreads();
  }

  // tmp[h] = sum_k riv[k]*wsf_t[k*512+h]  (2-way split over k)
  {
    float p = 0.f;
    const float* wp = wsf_t + half * 256 * 512 + h;
    for (int k = 0; k < 256; ++k) p += riv[half * 256 + k] * wp[k * 512];
    red2[t] = p;
  }
  __syncthreads();
  float tmp_h = red2[h] + red2[h + 512];
  __syncthreads();
  // tsum[h] = sum_l tanh(c_slot[b,l,h] + tmp_h)  (2-way split over l)
  const float* cp = c_slot + b * 64 * 512 + h;
  {
    float s = 0.f;
    for (int l = half * 32; l < half * 32 + 32; ++l) s += ftanh(cp[l * 512] + tmp_h);
    red2[t] = s;
  }
  __syncthreads();
  if (t < 512) va[t] = red2[t] + red2[t + 512];
  __syncthreads();
  // f[n] = sum_k va[k]*vsf_t[k*512+n]
  {
    float q = 0.f;
    const float* vp = vsf_t + half * 256 * 512 + h;
    for (int k = 0; k < 256; ++k) q += va[half * 256 + k] * vp[k * 512];
    red2[t] = q;
  }
  __syncthreads();
  float f_n = red2[h] + red2[h + 512];
  // r_slot[b,l,h] = f_n * c_slot[b,l,h]
  float* rp2 = r_slot + b * 64 * 512 + h;
  for (int l = half * 32; l < half * 32 + 32; ++l) rp2[l * 512] = f_n * cp[l * 512];
}

// ---- dominant kernel (unchanged from round 6) ----
__global__ __launch_bounds__(512, 4) void k_score(const float* __restrict__ hid,
                                                  const float* __restrict__ sf,
                                                  const short* __restrict__ wbp,
                                                  float* __restrict__ smat) {
  __shared__ short As[2][2048];
  __shared__ float red[8][64];
  const int i = blockIdx.x, b = blockIdx.y;
  const int t = threadIdx.x;
  const int w = t >> 6, lane = t & 63;
  const int lq = lane >> 4, lm = lane & 15;

  f32x4 acc[4][4];
#pragma unroll
  for (int r = 0; r < 4; ++r)
#pragma unroll
    for (int c = 0; c < 4; ++c) acc[r][c] = (f32x4){0.f, 0.f, 0.f, 0.f};

  const float* hrow = hid + (b * 64 + i) * 512;
  const float* sfb = sf + b * 64 * 512;

  const int fid = t >> 1, half = t & 1;
  const int am = (fid >> 6) * 16 + (fid & 15);
  const int ak = ((fid >> 4) & 3) * 8 + half * 4;
  const int aoff = fid * 8 + half * 4;

  const bf16x8* gb = (const bf16x8*)wbp + (w * 4) * 64 + lane;

  for (int ks = 0; ks < 16; ++ks) {
    const int buf = ks & 1;
    bf16x8 b0 = gb[ks * 2048];
    bf16x8 b1 = gb[ks * 2048 + 64];
    bf16x8 b2 = gb[ks * 2048 + 128];
    bf16x8 b3 = gb[ks * 2048 + 192];
    const float* hp = hrow + ks * 32 + ak;
    const float* sp = sfb + am * 512 + ks * 32 + ak;
    float4 hv = *(const float4*)hp;
    float4 sv = *(const float4*)sp;
    float t0 = ftanh(hv.x + sv.x);
    float t1 = ftanh(hv.y + sv.y);
    float t2 = ftanh(hv.z + sv.z);
    float t3 = ftanh(hv.w + sv.w);
    uint2 pk;
    pk.x = pack2(t0, t1);
    pk.y = pack2(t2, t3);
    *(uint2*)&As[buf][aoff] = pk;
    __syncthreads();
    bf16x8 af0 = *(const bf16x8*)&As[buf][(0 * 64 + lane) * 8];
    bf16x8 af1 = *(const bf16x8*)&As[buf][(1 * 64 + lane) * 8];
    bf16x8 af2 = *(const bf16x8*)&As[buf][(2 * 64 + lane) * 8];
    bf16x8 af3 = *(const bf16x8*)&As[buf][(3 * 64 + lane) * 8];
    acc[0][0] = __builtin_amdgcn_mfma_f32_16x16x32_bf16(af0, b0, acc[0][0], 0, 0, 0);
    acc[1][0] = __builtin_amdgcn_mfma_f32_16x16x32_bf16(af1, b0, acc[1][0], 0, 0, 0);
    acc[2][0] = __builtin_amdgcn_mfma_f32_16x16x32_bf16(af2, b0, acc[2][0], 0, 0, 0);
    acc[3][0] = __builtin_amdgcn_mfma_f32_16x16x32_bf16(af3, b0, acc[3][0], 0, 0, 0);
    acc[0][1] = __builtin_amdgcn_mfma_f32_16x16x32_bf16(af0, b1, acc[0][1], 0, 0, 0);
    acc[1][1] = __builtin_amdgcn_mfma_f32_16x16x32_bf16(af1, b1, acc[1][1], 0, 0, 0);
    acc[2][1] = __builtin_amdgcn_mfma_f32_16x16x32_bf16(af2, b1, acc[2][1], 0, 0, 0);
    acc[3][1] = __builtin_amdgcn_mfma_f32_16x16x32_bf16(af3, b1, acc[3][1], 0, 0, 0);
    acc[0][2] = __builtin_amdgcn_mfma_f32_16x16x32_bf16(af0, b2, acc[0][2], 0, 0, 0);
    acc[1][2] = __builtin_amdgcn_mfma_f32_16x16x32_bf16(af1, b2, acc[1][2], 0, 0, 0);
    acc[2][2] = __builtin_amdgcn_mfma_f32_16x16x32_bf16(af2, b2, acc[2][2], 0, 0, 0);
    acc[3][2] = __builtin_amdgcn_mfma_f32_16x16x32_bf16(af3, b2, acc[3][2], 0, 0, 0);
    acc[0][3] = __builtin_amdgcn_mfma_f32_16x16x32_bf16(af0, b3, acc[0][3], 0, 0, 0);
    acc[1][3] = __builtin_amdgcn_mfma_f32_16x16x32_bf16(af1, b3, acc[1][3], 0, 0, 0);
    acc[2][3] = __builtin_amdgcn_mfma_f32_16x16x32_bf16(af2, b3, acc[2][3], 0, 0, 0);
    acc[3][3] = __builtin_amdgcn_mfma_f32_16x16x32_bf16(af3, b3, acc[3][3], 0, 0, 0);
  }

#pragma unroll
  for (int r = 0; r < 4; ++r) {
#pragma unroll
    for (int reg = 0; reg < 4; ++reg) {
      float v = __expf(acc[r][0][reg]) + __expf(acc[r][1][reg]) +
                __expf(acc[r][2][reg]) + __expf(acc[r][3][reg]);
      v += __shfl_down(v, 8, 16);
      v += __shfl_down(v, 4, 16);
      v += __shfl_down(v, 2, 16);
      v += __shfl_down(v, 1, 16);
      if (lm == 0) red[w][r * 16 + lq * 4 + reg] = v;
    }
  }
  __syncthreads();
  if (t < 64) {
    float s = 0.f;
#pragma unroll
    for (int ww = 0; ww < 8; ++ww) s += red[ww][t];
    atomicAdd(&smat[i * 64 + t], s);
  }
}

// ---- intent with internal r_inte recompute. grid 16 (b), 256 thr ----
__global__ __launch_bounds__(256) void k_intent(const float* __restrict__ smat,
                                                const float* __restrict__ r_slot,
                                                const float* __restrict__ c_inte,
                                                const float* __restrict__ h,
                                                const float* __restrict__ wia_t,
                                                float* __restrict__ out) {
  __shared__ float av[64], riv[512], red[256];
  const int b = blockIdx.x;
  const int t = threadIdx.x;
  const int w = t >> 6, lane = t & 63;
  for (int r = w * 16; r < w * 16 + 16; ++r) {
    float v = smat[r * 64 + lane];
    float s = v;
    s += __shfl_xor(s, 1);
    s += __shfl_xor(s, 2);
    s += __shfl_xor(s, 4);
    s += __shfl_xor(s, 8);
    s += __shfl_xor(s, 16);
    s += __shfl_xor(s, 32);
    float d = __shfl(v, r);
    if (lane == 0) av[r] = d / s;
  }
  __syncthreads();
  for (int hh = t; hh < 512; hh += 256) {
    float a = 0.f;
    const float* rp = r_slot + b * 64 * 512 + hh;
    for (int i = 0; i < 64; ++i) a += av[i] * rp[i * 512];
    riv[hh] = a + c_inte[b * 512 + hh];
  }
  __syncthreads();
  const int n = t & 63, kq = t >> 6;
  const float* hrow = h + (b * 64 + 63) * 512;
  float p = 0.f;
  for (int k = kq * 128; k < kq * 128 + 128; ++k) {
    p += riv[k] * wia_t[k * 64 + n];
    p += hrow[k] * wia_t[(512 + k) * 64 + n];
  }
  red[t] = p;
  __syncthreads();
  if (t < 64) out[b * 64 + t] = red[t] + red[t + 64] + red[t + 128] + red[t + 192];
}

// slot[(b,l),n] = [h[b,l], r_slot[b,l]] @ W_sa[n,:]  via wsa_t
__global__ __launch_bounds__(256) void k_slot(const float* __restrict__ h,
                                              const float* __restrict__ r_slot,
                                              const float* __restrict__ wsa_t,
                                              float* __restrict__ out) {
  int idx = blockIdx.x * 256 + threadIdx.x;  // 65536
  int ml = idx >> 6, n = idx & 63;
  const float* x1 = h + ml * 512;
  const float* x2 = r_slot + ml * 512;
  float acc = 0.f;
  for (int k = 0; k < 512; k += 4) {
    float4 x = *(const float4*)(x1 + k);
    acc += x.x * wsa_t[k * 64 + n] + x.y * wsa_t[(k + 1) * 64 + n] +
           x.z * wsa_t[(k + 2) * 64 + n] + x.w * wsa_t[(k + 3) * 64 + n];
  }
  for (int k = 0; k < 512; k += 4) {
    float4 x = *(const float4*)(x2 + k);
    acc += x.x * wsa_t[(512 + k) * 64 + n] + x.y * wsa_t[(513 + k) * 64 + n] +
           x.z * wsa_t[(514 + k) * 64 + n] + x.w * wsa_t[(515 + k) * 64 + n];
  }
  out[idx] = acc;
}

extern "C" void kernel_launch(void* const* d_in, const int* in_sizes, int n_in,
                              void* d_out, int out_size, void* d_ws, size_t ws_size,
                              hipStream_t stream) {
  const float* h      = (const float*)d_in[0];
  const float* c_slot = (const float*)d_in[1];
  const float* c_inte = (const float*)d_in[2];
  const float* W_SF   = (const float*)d_in[3];
  const float* V_SF   = (const float*)d_in[4];
  const float* V1_ID  = (const float*)d_in[5];
  const float* V2_w   = (const float*)d_in[6];
  const float* V2_b   = (const float*)d_in[7];
  const float* W_ID   = (const float*)d_in[8];
  const float* W_ia   = (const float*)d_in[9];
  const float* W_sa   = (const float*)d_in[10];
  float* out = (float*)d_out;

  float* ws     = (float*)d_ws;
  short* wbp    = (short*)ws;
  short* v2h    = (short*)(ws + 131072);
  short* v2l    = (short*)(ws + 262144);
  short* v1h    = (short*)(ws + 393216);
  short* v1l    = (short*)(ws + 524288);
  float* sfbuf  = ws + 655360;    // 524288
  float* r_slot = ws + 1179648;   // 524288
  float* hid    = ws + 1703936;   // 524288
  float* smat   = ws + 2228224;   // 4096
  float* wsf_t  = ws + 2232320;   // 262144
  float* vsf_t  = ws + 2494464;   // 262144
  float* wia_t  = ws + 2756608;   // 65536
  float* wsa_t  = ws + 2822144;   // 65536

  k_prep_all<<<1184, 256, 0, stream>>>(W_ID, V2_w, V1_ID, W_SF, V_SF, W_ia, W_sa,
                                       wbp, v2h, v2l, v1h, v1l,
                                       wsf_t, vsf_t, wia_t, wsa_t);
  k_lin<<<dim3(64, 2), 256, 0, stream>>>(h, v2h, v2l, V2_b, sfbuf, nullptr);

  for (int it = 0; it < 3; ++it) {
    k_fused1<<<16, 1024, 0, stream>>>(it == 0 ? 1 : 0, smat, r_slot, c_inte,
                                      c_slot, wsf_t, vsf_t);
    k_lin<<<dim3(64, 2), 256, 0, stream>>>(r_slot, v1h, v1l, nullptr, hid, smat);
    k_score<<<dim3(64, 16), 512, 0, stream>>>(hid, sfbuf, wbp, smat);
  }

  k_intent<<<16, 256, 0, stream>>>(smat, r_slot, c_inte, h, wia_t, out);
  k_slot<<<256, 256, 0, stream>>>(h, r_slot, wsa_t, out + 1024);
}

// Round 8
// 380.639 us; speedup vs baseline: 6.5560x; 1.0944x over previous
//
#include <hip/hip_runtime.h>
#include <math.h>

// B=16, L=64, H=512, N_LABELS=64, ITERS=3
//
// ws layout (float offsets):
//   wbp 0 [131072] W_ID bf16 B-fragment-major
//   v2h 131072, v2l 262144, v1h 393216, v1l 524288 [131072 each]
//   sfbuf 655360, r_slot 1179648, hid 1703936 [524288 each]
//   smat 2228224 [4096], f 2232320 [8192]
//   wia_t 2240512, wsa_t 2306048 [65536 each]

typedef __attribute__((ext_vector_type(8))) short bf16x8;
typedef __attribute__((ext_vector_type(4))) float f32x4;

__device__ inline short f2bf(float x) {  // RNE
  unsigned u = __float_as_uint(x);
  unsigned r = (u + 0x7fffu + ((u >> 16) & 1u)) >> 16;
  return (short)r;
}
__device__ inline float bf2f(short s) {
  return __uint_as_float(((unsigned)(unsigned short)s) << 16);
}
__device__ inline unsigned pack2(float a, float b) {  // truncating 2xbf16
  return (__float_as_uint(a) >> 16) | (__float_as_uint(b) & 0xffff0000u);
}
__device__ inline float ftanh(float x) {
  float t = __expf(2.f * x);
  return 1.f - 2.f * __builtin_amdgcn_rcpf(t + 1.f);
}

// ---- prep: packs + wia/wsa transposes ----
__global__ __launch_bounds__(256) void k_prep(
    const float* __restrict__ W_ID, const float* __restrict__ V2,
    const float* __restrict__ V1, const float* __restrict__ W_ia,
    const float* __restrict__ W_sa, short* __restrict__ wbp,
    short* __restrict__ v2h, short* __restrict__ v2l,
    short* __restrict__ v1h, short* __restrict__ v1l,
    float* __restrict__ wia_t, float* __restrict__ wsa_t) {
  const int bx = blockIdx.x;
  const int t = threadIdx.x;
  if (bx < 1024) {
    int idx = bx * 256 + t;  // 262144
    int j = idx & 7, lane = (idx >> 3) & 63;
    int ntile = (idx >> 9) & 31, kstep = idx >> 14;
    int g = ntile * 16 + (lane & 15);
    int h = kstep * 32 + (lane >> 4) * 8 + j;
    int src = g * 512 + h;
    wbp[idx] = f2bf(W_ID[src]);
    float x2 = V2[src];
    short h2 = f2bf(x2);
    v2h[idx] = h2;
    v2l[idx] = f2bf(x2 - bf2f(h2));
    float x1 = V1[src];
    short h1 = f2bf(x1);
    v1h[idx] = h1;
    v1l[idx] = f2bf(x1 - bf2f(h1));
  } else {
    const float* tin;
    float* tout;
    int c0;
    if (bx < 1040) { tin = W_ia; tout = wia_t; c0 = (bx - 1024) * 64; }
    else           { tin = W_sa; tout = wsa_t; c0 = (bx - 1040) * 64; }
    // R=64, C=1024
    __shared__ float tile[64][65];
    const int tx = t & 63, ty = t >> 6;
#pragma unroll
    for (int it2 = 0; it2 < 16; ++it2) {
      int rl = ty + it2 * 4;
      tile[rl][tx] = tin[rl * 1024 + c0 + tx];
    }
    __syncthreads();
#pragma unroll
    for (int it2 = 0; it2 < 16; ++it2) {
      int cl = ty + it2 * 4;
      tout[(c0 + cl) * 64 + tx] = tile[tx][cl];
    }
  }
}

// ---- split-precision MFMA linear: C[M,512] = A[M,512] @ W[512,512]^T (+bias)
// mode0 (f==null): A read directly.  mode1 (f!=null): A = f[b,:] (x) c_slot,
// and nh==0 blocks write r_slot rows as a side effect.
// A global loads software-pipelined one K-step ahead.
__global__ __launch_bounds__(256) void k_lin(const float* __restrict__ A,
                                             const float* __restrict__ c_slot,
                                             const float* __restrict__ f,
                                             const short* __restrict__ bh,
                                             const short* __restrict__ bl,
                                             const float* __restrict__ bias,
                                             float* __restrict__ C,
                                             float* __restrict__ rs_out,
                                             float* __restrict__ smat0,
                                             float* __restrict__ fzero) {
  __shared__ short Ah[2][512], Al[2][512];
  __shared__ float fl[512];
  const int m0 = blockIdx.x * 16;
  const int nh = blockIdx.y;
  const int t = threadIdx.x;
  if (smat0 && nh == 0 && blockIdx.x < 8) {
    smat0[blockIdx.x * 512 + t] = 0.f;
    smat0[blockIdx.x * 512 + 256 + t] = 0.f;
  }
  if (fzero && nh == 1 && blockIdx.x < 16) {
    fzero[blockIdx.x * 512 + t] = 0.f;
    fzero[blockIdx.x * 512 + 256 + t] = 0.f;
  }
  if (f) {
    fl[t] = f[(blockIdx.x >> 2) * 512 + t];
    fl[t + 256] = f[(blockIdx.x >> 2) * 512 + 256 + t];
  }
  const int w = t >> 6, lane = t & 63;
  const int lq = lane >> 4, lm = lane & 15;
  f32x4 acc[4];
#pragma unroll
  for (int c = 0; c < 4; ++c) acc[c] = (f32x4){0.f, 0.f, 0.f, 0.f};

  const bf16x8* gbh = (const bf16x8*)bh + (nh * 16 + w * 4) * 64 + lane;
  const bf16x8* gbl = (const bf16x8*)bl + (nh * 16 + w * 4) * 64 + lane;

  const int la = t >> 2, j0 = (t & 3) * 2;
  const int m = la & 15, kk = (la >> 4) * 8 + j0;
  const float* abase = (f ? c_slot : A) + (m0 + m) * 512 + kk;
  float* rbase = rs_out + (m0 + m) * 512 + kk;
  if (f) __syncthreads();  // fl ready
  float2 x = *(const float2*)abase;

  for (int ks = 0; ks < 16; ++ks) {
    const int buf = ks & 1;
    bf16x8 b0h = gbh[ks * 2048];
    bf16x8 b1h = gbh[ks * 2048 + 64];
    bf16x8 b2h = gbh[ks * 2048 + 128];
    bf16x8 b3h = gbh[ks * 2048 + 192];
    bf16x8 b0l = gbl[ks * 2048];
    bf16x8 b1l = gbl[ks * 2048 + 64];
    bf16x8 b2l = gbl[ks * 2048 + 128];
    bf16x8 b3l = gbl[ks * 2048 + 192];
    float2 xn = x;
    if (ks < 15) xn = *(const float2*)(abase + (ks + 1) * 32);
    float a0 = x.x, a1 = x.y;
    if (f) {
      a0 *= fl[ks * 32 + kk];
      a1 *= fl[ks * 32 + kk + 1];
      if (nh == 0) *(float2*)(rbase + ks * 32) = make_float2(a0, a1);
    }
    short h0 = f2bf(a0), h1 = f2bf(a1);
    short l0 = f2bf(a0 - bf2f(h0)), l1 = f2bf(a1 - bf2f(h1));
    *(short2*)&Ah[buf][t * 2] = make_short2(h0, h1);
    *(short2*)&Al[buf][t * 2] = make_short2(l0, l1);
    __syncthreads();
    bf16x8 ah = *(const bf16x8*)&Ah[buf][lane * 8];
    bf16x8 al = *(const bf16x8*)&Al[buf][lane * 8];
    acc[0] = __builtin_amdgcn_mfma_f32_16x16x32_bf16(ah, b0h, acc[0], 0, 0, 0);
    acc[0] = __builtin_amdgcn_mfma_f32_16x16x32_bf16(al, b0h, acc[0], 0, 0, 0);
    acc[0] = __builtin_amdgcn_mfma_f32_16x16x32_bf16(ah, b0l, acc[0], 0, 0, 0);
    acc[1] = __builtin_amdgcn_mfma_f32_16x16x32_bf16(ah, b1h, acc[1], 0, 0, 0);
    acc[1] = __builtin_amdgcn_mfma_f32_16x16x32_bf16(al, b1h, acc[1], 0, 0, 0);
    acc[1] = __builtin_amdgcn_mfma_f32_16x16x32_bf16(ah, b1l, acc[1], 0, 0, 0);
    acc[2] = __builtin_amdgcn_mfma_f32_16x16x32_bf16(ah, b2h, acc[2], 0, 0, 0);
    acc[2] = __builtin_amdgcn_mfma_f32_16x16x32_bf16(al, b2h, acc[2], 0, 0, 0);
    acc[2] = __builtin_amdgcn_mfma_f32_16x16x32_bf16(ah, b2l, acc[2], 0, 0, 0);
    acc[3] = __builtin_amdgcn_mfma_f32_16x16x32_bf16(ah, b3h, acc[3], 0, 0, 0);
    acc[3] = __builtin_amdgcn_mfma_f32_16x16x32_bf16(al, b3h, acc[3], 0, 0, 0);
    acc[3] = __builtin_amdgcn_mfma_f32_16x16x32_bf16(ah, b3l, acc[3], 0, 0, 0);
    x = xn;
  }
#pragma unroll
  for (int c = 0; c < 4; ++c)
#pragma unroll
    for (int reg = 0; reg < 4; ++reg) {
      int mm = m0 + lq * 4 + reg;
      int n = nh * 256 + (w * 4 + c) * 16 + lm;
      float v = acc[c][reg];
      if (bias) v += bias[n];
      C[mm * 512 + n] = v;
    }
}

// ---- per-iteration mid chain: atts + riv (redundant per block) + tmp +
//      tanh-sum + f partials (atomic).  grid 64 = (b 16 x quarter 4), 512 thr.
__global__ __launch_bounds__(512) void k_mid(int first,
                                             const float* __restrict__ smat,
                                             const float* __restrict__ r_slot,
                                             const float* __restrict__ c_inte,
                                             const float* __restrict__ c_slot,
                                             const float* __restrict__ W_SF,
                                             const float* __restrict__ V_SF,
                                             float* __restrict__ f) {
  __shared__ float av[64];
  __shared__ float rl[512];
  __shared__ float red[512];
  __shared__ float tm[128];
  __shared__ float ts[128];
  const int b = blockIdx.x >> 2, q = blockIdx.x & 3;
  const int t = threadIdx.x;

  if (first) {
    rl[t] = c_inte[b * 512 + t];
    __syncthreads();
  } else {
    if (t < 256) {
      int w = t >> 6, lane = t & 63;
      for (int r = w * 16; r < w * 16 + 16; ++r) {
        float v = smat[r * 64 + lane];
        float s = v;
        s += __shfl_xor(s, 1);
        s += __shfl_xor(s, 2);
        s += __shfl_xor(s, 4);
        s += __shfl_xor(s, 8);
        s += __shfl_xor(s, 16);
        s += __shfl_xor(s, 32);
        float d = __shfl(v, r);
        if (lane == 0) av[r] = d / s;
      }
    }
    __syncthreads();
    float a = 0.f;
    const float* rp = r_slot + b * 64 * 512 + t;
#pragma unroll 8
    for (int i = 0; i < 64; ++i) a += av[i] * rp[i * 512];
    rl[t] = a + c_inte[b * 512 + t];
    __syncthreads();
  }

  // tmp partials: h = q*128 + (t>>2), k-chunk = (t&3)*128
  {
    const int hh = q * 128 + (t >> 2), kq = t & 3;
    const float* wr = W_SF + hh * 512 + kq * 128;
    const float* rv = rl + kq * 128;
    float p = 0.f;
    for (int k = 0; k < 128; k += 4) {
      float4 wv = *(const float4*)(wr + k);
      p += rv[k] * wv.x + rv[k + 1] * wv.y + rv[k + 2] * wv.z + rv[k + 3] * wv.w;
    }
    red[t] = p;
  }
  __syncthreads();
  if (t < 128) tm[t] = red[t * 4] + red[t * 4 + 1] + red[t * 4 + 2] + red[t * 4 + 3];
  __syncthreads();
  // tanh-sum partials: h = q*128 + (t>>2), l-chunk = (t&3)*16
  {
    const int hh = q * 128 + (t >> 2), lc = t & 3;
    float tmp_h = tm[t >> 2];
    const float* cp = c_slot + (b * 64 + lc * 16) * 512 + hh;
    float s = 0.f;
    for (int l = 0; l < 16; ++l) s += ftanh(cp[l * 512] + tmp_h);
    red[t] = s;
  }
  __syncthreads();
  if (t < 128) ts[t] = red[t * 4] + red[t * 4 + 1] + red[t * 4 + 2] + red[t * 4 + 3];
  __syncthreads();
  // f partials: n = t, k in this block's quarter
  {
    const float* vr = V_SF + t * 512 + q * 128;
    float p = 0.f;
    for (int k = 0; k < 128; k += 4) {
      float4 vv = *(const float4*)(vr + k);
      p += ts[k] * vv.x + ts[k + 1] * vv.y + ts[k + 2] * vv.z + ts[k + 3] * vv.w;
    }
    atomicAdd(&f[b * 512 + t], p);
  }
}

// ---- dominant kernel: A-loads software-pipelined one K-step ahead ----
__global__ __launch_bounds__(512, 4) void k_score(const float* __restrict__ hid,
                                                  const float* __restrict__ sf,
                                                  const short* __restrict__ wbp,
                                                  float* __restrict__ smat,
                                                  float* __restrict__ fz) {
  __shared__ short As[2][2048];
  __shared__ float red[8][64];
  const int i = blockIdx.x, b = blockIdx.y;
  const int t = threadIdx.x;
  if (fz && i == 0) fz[b * 512 + t] = 0.f;
  const int w = t >> 6, lane = t & 63;
  const int lq = lane >> 4, lm = lane & 15;

  f32x4 acc[4][4];
#pragma unroll
  for (int r = 0; r < 4; ++r)
#pragma unroll
    for (int c = 0; c < 4; ++c) acc[r][c] = (f32x4){0.f, 0.f, 0.f, 0.f};

  const float* hrow = hid + (b * 64 + i) * 512;
  const float* sfb = sf + b * 64 * 512;

  const int fid = t >> 1, half = t & 1;
  const int am = (fid >> 6) * 16 + (fid & 15);
  const int ak = ((fid >> 4) & 3) * 8 + half * 4;
  const int aoff = fid * 8 + half * 4;

  const bf16x8* gb = (const bf16x8*)wbp + (w * 4) * 64 + lane;
  const float* hp0 = hrow + ak;
  const float* sp0 = sfb + am * 512 + ak;
  float4 hv = *(const float4*)hp0;
  float4 sv = *(const float4*)sp0;

  for (int ks = 0; ks < 16; ++ks) {
    const int buf = ks & 1;
    bf16x8 b0 = gb[ks * 2048];
    bf16x8 b1 = gb[ks * 2048 + 64];
    bf16x8 b2 = gb[ks * 2048 + 128];
    bf16x8 b3 = gb[ks * 2048 + 192];
    float4 hvn = hv, svn = sv;
    if (ks < 15) {
      hvn = *(const float4*)(hp0 + (ks + 1) * 32);
      svn = *(const float4*)(sp0 + (ks + 1) * 32);
    }
    float t0 = ftanh(hv.x + sv.x);
    float t1 = ftanh(hv.y + sv.y);
    float t2 = ftanh(hv.z + sv.z);
    float t3 = ftanh(hv.w + sv.w);
    uint2 pk;
    pk.x = pack2(t0, t1);
    pk.y = pack2(t2, t3);
    *(uint2*)&As[buf][aoff] = pk;
    __syncthreads();
    bf16x8 af0 = *(const bf16x8*)&As[buf][(0 * 64 + lane) * 8];
    bf16x8 af1 = *(const bf16x8*)&As[buf][(1 * 64 + lane) * 8];
    bf16x8 af2 = *(const bf16x8*)&As[buf][(2 * 64 + lane) * 8];
    bf16x8 af3 = *(const bf16x8*)&As[buf][(3 * 64 + lane) * 8];
    acc[0][0] = __builtin_amdgcn_mfma_f32_16x16x32_bf16(af0, b0, acc[0][0], 0, 0, 0);
    acc[1][0] = __builtin_amdgcn_mfma_f32_16x16x32_bf16(af1, b0, acc[1][0], 0, 0, 0);
    acc[2][0] = __builtin_amdgcn_mfma_f32_16x16x32_bf16(af2, b0, acc[2][0], 0, 0, 0);
    acc[3][0] = __builtin_amdgcn_mfma_f32_16x16x32_bf16(af3, b0, acc[3][0], 0, 0, 0);
    acc[0][1] = __builtin_amdgcn_mfma_f32_16x16x32_bf16(af0, b1, acc[0][1], 0, 0, 0);
    acc[1][1] = __builtin_amdgcn_mfma_f32_16x16x32_bf16(af1, b1, acc[1][1], 0, 0, 0);
    acc[2][1] = __builtin_amdgcn_mfma_f32_16x16x32_bf16(af2, b1, acc[2][1], 0, 0, 0);
    acc[3][1] = __builtin_amdgcn_mfma_f32_16x16x32_bf16(af3, b1, acc[3][1], 0, 0, 0);
    acc[0][2] = __builtin_amdgcn_mfma_f32_16x16x32_bf16(af0, b2, acc[0][2], 0, 0, 0);
    acc[1][2] = __builtin_amdgcn_mfma_f32_16x16x32_bf16(af1, b2, acc[1][2], 0, 0, 0);
    acc[2][2] = __builtin_amdgcn_mfma_f32_16x16x32_bf16(af2, b2, acc[2][2], 0, 0, 0);
    acc[3][2] = __builtin_amdgcn_mfma_f32_16x16x32_bf16(af3, b2, acc[3][2], 0, 0, 0);
    acc[0][3] = __builtin_amdgcn_mfma_f32_16x16x32_bf16(af0, b3, acc[0][3], 0, 0, 0);
    acc[1][3] = __builtin_amdgcn_mfma_f32_16x16x32_bf16(af1, b3, acc[1][3], 0, 0, 0);
    acc[2][3] = __builtin_amdgcn_mfma_f32_16x16x32_bf16(af2, b3, acc[2][3], 0, 0, 0);
    acc[3][3] = __builtin_amdgcn_mfma_f32_16x16x32_bf16(af3, b3, acc[3][3], 0, 0, 0);
    hv = hvn;
    sv = svn;
  }

#pragma unroll
  for (int r = 0; r < 4; ++r) {
#pragma unroll
    for (int reg = 0; reg < 4; ++reg) {
      float v = __expf(acc[r][0][reg]) + __expf(acc[r][1][reg]) +
                __expf(acc[r][2][reg]) + __expf(acc[r][3][reg]);
      v += __shfl_down(v, 8, 16);
      v += __shfl_down(v, 4, 16);
      v += __shfl_down(v, 2, 16);
      v += __shfl_down(v, 1, 16);
      if (lm == 0) red[w][r * 16 + lq * 4 + reg] = v;
    }
  }
  __syncthreads();
  if (t < 64) {
    float s = 0.f;
#pragma unroll
    for (int ww = 0; ww < 8; ++ww) s += red[ww][t];
    atomicAdd(&smat[i * 64 + t], s);
  }
}

// ---- intent with internal r_inte recompute. grid 16 (b), 256 thr ----
__global__ __launch_bounds__(256) void k_intent(const float* __restrict__ smat,
                                                const float* __restrict__ r_slot,
                                                const float* __restrict__ c_inte,
                                                const float* __restrict__ h,
                                                const float* __restrict__ wia_t,
                                                float* __restrict__ out) {
  __shared__ float av[64], riv[512], red[256];
  const int b = blockIdx.x;
  const int t = threadIdx.x;
  const int w = t >> 6, lane = t & 63;
  for (int r = w * 16; r < w * 16 + 16; ++r) {
    float v = smat[r * 64 + lane];
    float s = v;
    s += __shfl_xor(s, 1);
    s += __shfl_xor(s, 2);
    s += __shfl_xor(s, 4);
    s += __shfl_xor(s, 8);
    s += __shfl_xor(s, 16);
    s += __shfl_xor(s, 32);
    float d = __shfl(v, r);
    if (lane == 0) av[r] = d / s;
  }
  __syncthreads();
  for (int hh = t; hh < 512; hh += 256) {
    float a = 0.f;
    const float* rp = r_slot + b * 64 * 512 + hh;
    for (int i = 0; i < 64; ++i) a += av[i] * rp[i * 512];
    riv[hh] = a + c_inte[b * 512 + hh];
  }
  __syncthreads();
  const int n = t & 63, kq = t >> 6;
  const float* hrow = h + (b * 64 + 63) * 512;
  float p = 0.f;
  for (int k = kq * 128; k < kq * 128 + 128; ++k) {
    p += riv[k] * wia_t[k * 64 + n];
    p += hrow[k] * wia_t[(512 + k) * 64 + n];
  }
  red[t] = p;
  __syncthreads();
  if (t < 64) out[b * 64 + t] = red[t] + red[t + 64] + red[t + 128] + red[t + 192];
}

// slot[(b,l),n] = [h[b,l], r_slot[b,l]] @ W_sa[n,:]  via wsa_t
__global__ __launch_bounds__(256) void k_slot(const float* __restrict__ h,
                                              const float* __restrict__ r_slot,
                                              const float* __restrict__ wsa_t,
                                              float* __restrict__ out) {
  int idx = blockIdx.x * 256 + threadIdx.x;  // 65536
  int ml = idx >> 6, n = idx & 63;
  const float* x1 = h + ml * 512;
  const float* x2 = r_slot + ml * 512;
  float acc = 0.f;
  for (int k = 0; k < 512; k += 4) {
    float4 x = *(const float4*)(x1 + k);
    acc += x.x * wsa_t[k * 64 + n] + x.y * wsa_t[(k + 1) * 64 + n] +
           x.z * wsa_t[(k + 2) * 64 + n] + x.w * wsa_t[(k + 3) * 64 + n];
  }
  for (int k = 0; k < 512; k += 4) {
    float4 x = *(const float4*)(x2 + k);
    acc += x.x * wsa_t[(512 + k) * 64 + n] + x.y * wsa_t[(513 + k) * 64 + n] +
           x.z * wsa_t[(514 + k) * 64 + n] + x.w * wsa_t[(515 + k) * 64 + n];
  }
  out[idx] = acc;
}

extern "C" void kernel_launch(void* const* d_in, const int* in_sizes, int n_in,
                              void* d_out, int out_size, void* d_ws, size_t ws_size,
                              hipStream_t stream) {
  const float* h      = (const float*)d_in[0];
  const float* c_slot = (const float*)d_in[1];
  const float* c_inte = (const float*)d_in[2];
  const float* W_SF   = (const float*)d_in[3];
  const float* V_SF   = (const float*)d_in[4];
  const float* V1_ID  = (const float*)d_in[5];
  const float* V2_w   = (const float*)d_in[6];
  const float* V2_b   = (const float*)d_in[7];
  const float* W_ID   = (const float*)d_in[8];
  const float* W_ia   = (const float*)d_in[9];
  const float* W_sa   = (const float*)d_in[10];
  float* out = (float*)d_out;

  float* ws     = (float*)d_ws;
  short* wbp    = (short*)ws;
  short* v2h    = (short*)(ws + 131072);
  short* v2l    = (short*)(ws + 262144);
  short* v1h    = (short*)(ws + 393216);
  short* v1l    = (short*)(ws + 524288);
  float* sfbuf  = ws + 655360;    // 524288
  float* r_slot = ws + 1179648;   // 524288
  float* hid    = ws + 1703936;   // 524288
  float* smat   = ws + 2228224;   // 4096
  float* f      = ws + 2232320;   // 8192
  float* wia_t  = ws + 2240512;   // 65536
  float* wsa_t  = ws + 2306048;   // 65536

  k_prep<<<1056, 256, 0, stream>>>(W_ID, V2_w, V1_ID, W_ia, W_sa,
                                   wbp, v2h, v2l, v1h, v1l, wia_t, wsa_t);
  // sfbuf = h @ V2^T + b  (mode0); spare blocks zero f for first k_mid
  k_lin<<<dim3(64, 2), 256, 0, stream>>>(h, nullptr, nullptr, v2h, v2l, V2_b,
                                         sfbuf, r_slot, nullptr, f);

  for (int it = 0; it < 3; ++it) {
    k_mid<<<64, 512, 0, stream>>>(it == 0 ? 1 : 0, smat, r_slot, c_inte,
                                  c_slot, W_SF, V_SF, f);
    // hid = (f (x) c_slot) @ V1^T; writes r_slot; zeroes smat
    k_lin<<<dim3(64, 2), 256, 0, stream>>>(nullptr, c_slot, f, v1h, v1l,
                                           nullptr, hid, r_slot, smat, nullptr);
    // score; blocks i==0 zero f for next k_mid
    k_score<<<dim3(64, 16), 512, 0, stream>>>(hid, sfbuf, wbp, smat, f);
  }

  k_intent<<<16, 256, 0, stream>>>(smat, r_slot, c_inte, h, wia_t, out);
  k_slot<<<256, 256, 0, stream>>>(h, r_slot, wsa_t, out + 1024);
}